// Round 1
// 315.030 us; speedup vs baseline: 1.2249x; 1.2249x over previous
//
#include <hip/hip_runtime.h>
#include <hip/hip_bf16.h>

#define NN 100000
#define EE 1600000
#define NB_SCAN 391   // ceil(NN/256)

// ---- bucketed CSR parameters ----
#define NBUCK 782     // dst>>7 -> 782 buckets of 128 nodes
#define CPAD  16      // cursor padding (64B) to kill line contention
#define NCB   128     // count blocks in fusedA
#define NPART 391     // partition blocks (4096 edges each)
#define NE4   400000  // EE/4

typedef __hip_bfloat16 bf16_t;
typedef int int4v __attribute__((ext_vector_type(4)));
typedef float f4 __attribute__((ext_vector_type(4)));

// ---- workspace layout (float offsets) ----
#define PARB  600000       // params fp32            4465
#define EMB   604480       // N*32 raw (pre-bn1) embeddings
#define PBUF  3804480      // N*32  P' (bn1+Wmsg folded)
#define QBUF  7004480      // N*32  Q  (bn1+Wmsg folded)
#define ABUF  10204480     // N*32  agg; ALSO aliased as pe2[EE] (int2) before k_gather
#define SOFF  13404480     // stats: [0:32) sum1 [32:64) sq1 [64:96) sum2 [96:128) sq2, [128] flag
#define CURS  (SOFF + 256)           // NBUCK*CPAD ints (padded bucket counters/cursors)
#define BASEO (CURS + 12512)         // NBUCK+1 ints (bucket bases)
#define ROWP  (BASEO + 1024)         // 100001 ints
#define SRCL  (ROWP + 100002)        // 1600000 ints

// ---- param offsets inside PARB ----
#define O_WCONT 0
#define O_BCONT 96
#define O_TCHRG 112
#define O_TPDG  136
#define O_TPV   192
#define O_WCAT  256
#define O_BCAT  640
#define O_WENC  656
#define O_BENC  1680
#define O_GALL  1712
#define O_BEALL 1744
#define O_WMSG  1776
#define O_BMSG  3824
#define O_GCONV 3856
#define O_BECONV 3888
#define O_WOUT1 3920
#define O_BOUT1 4432
#define O_WOUT2 4448
#define O_BOUT2 4464
#define NPAR    4465

__device__ __forceinline__ float bf(unsigned short u) {
    return __uint_as_float(((unsigned)u) << 16);
}
__device__ __forceinline__ f4 elu4(f4 v) {
    f4 r;
    r.x = v.x > 0.0f ? v.x : expm1f(v.x);
    r.y = v.y > 0.0f ? v.y : expm1f(v.y);
    r.z = v.z > 0.0f ? v.z : expm1f(v.z);
    r.w = v.w > 0.0f ? v.w : expm1f(v.w);
    return r;
}

// ---------------- dtype detection (bf16 vs f32 tensors) ----------------
__global__ __launch_bounds__(64) void k_detect(const unsigned short* __restrict__ w,
                                               int* __restrict__ flag)
{
    int bad = 0;
    for (int i = threadIdx.x; i < 1024; i += 64) {
        unsigned e = (w[i] >> 7) & 0xFFu;
        if (e >= 137u) bad = 1;           // |v| >= 2^10 as bf16 -> impossible for real weights
    }
    unsigned long long m = __ballot(bad);
    if (threadIdx.x == 0) *flag = (m != 0ull) ? 1 : 0;
}

// ---------------- init: zero cursors & stats; block 0 converts params ----------------
struct InitArgs {
    const void* p[19];
    const int*  flag;
    float*      par;
    int*        curs;
    float*      stats;
};

__global__ __launch_bounds__(256) void k_init(InitArgs a)
{
    const int offs[20] = {O_WCONT,O_BCONT,O_TCHRG,O_TPDG,O_TPV,O_WCAT,O_BCAT,O_WENC,
                          O_BENC,O_GALL,O_BEALL,O_WMSG,O_BMSG,O_GCONV,O_BECONV,
                          O_WOUT1,O_BOUT1,O_WOUT2,O_BOUT2,NPAR};
    int b = blockIdx.x, tid = threadIdx.x;
    int g = b * 256 + tid;
    if (g < NBUCK * CPAD) a.curs[g] = 0;
    if (g < 128) a.stats[g] = 0.0f;
    if (b == 0) {
        int f32 = *a.flag;
        for (int i = tid; i < NPAR; i += 256) {
            int t = 0;
            while (offs[t + 1] <= i) t++;
            int l = i - offs[t];
            const void* s = a.p[t];
            a.par[i] = f32 ? ((const float*)s)[l] : bf(((const unsigned short*)s)[l]);
        }
    }
}

// ---------------- fused A: bucket-count (blocks < NCB) | embed (blocks >= NCB) ----------------
__global__ __launch_bounds__(256, 1) void k_fusedA(
    const int* __restrict__ eidx, int* __restrict__ curs,
    const void* __restrict__ xc, const int* __restrict__ x_cat,
    const float* __restrict__ par, const int* __restrict__ flag,
    float* __restrict__ emb)
{
    __shared__ f4 sWc4[24];     // W_cont [6][16]
    __shared__ f4 sbc4[4];
    __shared__ f4 sTc4[6], sTp4[14], sTv4[16];
    __shared__ f4 sWcat4[96];   // [24][16]
    __shared__ f4 sbcat4[4];
    __shared__ f4 sWe4[256];    // [32][32]
    __shared__ f4 sbe4[8];
    int tid = threadIdx.x;
    int b = blockIdx.x;

    if (b < NCB) {
        // ---- LDS-private bucket histogram of dst>>7 ----
        __shared__ int cnt[NBUCK];
        for (int i = tid; i < NBUCK; i += 256) cnt[i] = 0;
        __syncthreads();
        const int4v* dst4 = (const int4v*)(eidx + EE);
        int i0 = b * (NE4 / NCB);          // 3125 int4 per block
        int i1 = i0 + (NE4 / NCB);
        for (int i = i0 + tid; i < i1; i += 256) {
            int4v d = __builtin_nontemporal_load(&dst4[i]);
            atomicAdd(&cnt[d.x >> 7], 1);
            atomicAdd(&cnt[d.y >> 7], 1);
            atomicAdd(&cnt[d.z >> 7], 1);
            atomicAdd(&cnt[d.w >> 7], 1);
        }
        __syncthreads();
        for (int i = tid; i < NBUCK; i += 256) {
            int c = cnt[i];
            if (c) atomicAdd(&curs[i * CPAD], c);   // no-return, padded
        }
        return;
    }

    // ---- embed path ----
    {
        float* s;
        s=(float*)sWc4;   for(int i=tid;i<96;  i+=256) s[i]=par[O_WCONT+i];
        s=(float*)sbc4;   for(int i=tid;i<16;  i+=256) s[i]=par[O_BCONT+i];
        s=(float*)sTc4;   for(int i=tid;i<24;  i+=256) s[i]=par[O_TCHRG+i];
        s=(float*)sTp4;   for(int i=tid;i<56;  i+=256) s[i]=par[O_TPDG+i];
        s=(float*)sTv4;   for(int i=tid;i<64;  i+=256) s[i]=par[O_TPV+i];
        s=(float*)sWcat4; for(int i=tid;i<384; i+=256) s[i]=par[O_WCAT+i];
        s=(float*)sbcat4; for(int i=tid;i<16;  i+=256) s[i]=par[O_BCAT+i];
        s=(float*)sWe4;   for(int i=tid;i<1024;i+=256) s[i]=par[O_WENC+i];
        s=(float*)sbe4;   for(int i=tid;i<32;  i+=256) s[i]=par[O_BENC+i];
    }
    __syncthreads();

    int n = (b - NCB) * 256 + tid;
    if (n >= NN) return;

    float x0,x1,x2,x3,x4,x5;
    if (*flag) {
        const float* xr = (const float*)xc + (size_t)n * 6;
        x0=xr[0]; x1=xr[1]; x2=xr[2]; x3=xr[3]; x4=xr[4]; x5=xr[5];
    } else {
        const unsigned* xr = (const unsigned*)xc + (size_t)n * 3;
        unsigned w0=xr[0], w1=xr[1], w2=xr[2];
        x0=__uint_as_float(w0<<16); x1=__uint_as_float(w0 & 0xFFFF0000u);
        x2=__uint_as_float(w1<<16); x3=__uint_as_float(w1 & 0xFFFF0000u);
        x4=__uint_as_float(w2<<16); x5=__uint_as_float(w2 & 0xFFFF0000u);
    }

    f4 ec[4];
    #pragma unroll
    for (int g = 0; g < 4; g++) {
        f4 a = sbc4[g];
        a += x0 * sWc4[0*4+g]; a += x1 * sWc4[1*4+g]; a += x2 * sWc4[2*4+g];
        a += x3 * sWc4[3*4+g]; a += x4 * sWc4[4*4+g]; a += x5 * sWc4[5*4+g];
        ec[g] = elu4(a);
    }

    int c0 = x_cat[n*3+0], c1 = x_cat[n*3+1], c2 = x_cat[n*3+2];
    int a0 = c0 < 0 ? -c0 : c0;
    int pi = (a0==1)?0:(a0==2)?1:(a0==11)?2:(a0==13)?3:(a0==22)?4:(a0==130)?5:6;
    int ci = c1 + 1;

    f4 t0a = sTc4[ci*2],  t0b = sTc4[ci*2+1];
    f4 t1a = sTp4[pi*2],  t1b = sTp4[pi*2+1];
    f4 t2a = sTv4[c2*2],  t2b = sTv4[c2*2+1];

    f4 ecat[4];
    #pragma unroll
    for (int g = 0; g < 4; g++) {
        f4 a = sbcat4[g];
        #pragma unroll
        for (int k = 0; k < 4; k++) a += t0a[k] * sWcat4[(k     )*4+g];
        #pragma unroll
        for (int k = 0; k < 4; k++) a += t0b[k] * sWcat4[(4 + k )*4+g];
        #pragma unroll
        for (int k = 0; k < 4; k++) a += t1a[k] * sWcat4[(8 + k )*4+g];
        #pragma unroll
        for (int k = 0; k < 4; k++) a += t1b[k] * sWcat4[(12 + k)*4+g];
        #pragma unroll
        for (int k = 0; k < 4; k++) a += t2a[k] * sWcat4[(16 + k)*4+g];
        #pragma unroll
        for (int k = 0; k < 4; k++) a += t2b[k] * sWcat4[(20 + k)*4+g];
        ecat[g] = elu4(a);
    }

    f4* o = (f4*)(emb + (size_t)n * 32);
    #pragma unroll
    for (int cg = 0; cg < 8; cg++) {
        f4 a = sbe4[cg];
        #pragma unroll
        for (int kg = 0; kg < 4; kg++) {
            #pragma unroll
            for (int k = 0; k < 4; k++)
                a += ecat[kg][k] * sWe4[(kg*4+k)*8 + cg];
        }
        #pragma unroll
        for (int kg = 0; kg < 4; kg++) {
            #pragma unroll
            for (int k = 0; k < 4; k++)
                a += ec[kg][k] * sWe4[(16 + kg*4+k)*8 + cg];
        }
        o[cg] = elu4(a);
    }
}

// ---------------- scan of 782 bucket counts -> bases; cursors := base ----------------
__global__ __launch_bounds__(1024) void k_scan782(int* __restrict__ curs,
                                                  int* __restrict__ base,
                                                  int* __restrict__ rowp)
{
    __shared__ int s[1024];
    int tid = threadIdx.x;
    int v = (tid < NBUCK) ? curs[tid * CPAD] : 0;
    s[tid] = v;
    __syncthreads();
    for (int off = 1; off < 1024; off <<= 1) {
        int x = (tid >= off) ? s[tid - off] : 0;
        __syncthreads();
        s[tid] += x;
        __syncthreads();
    }
    if (tid < NBUCK) {
        int bexc = s[tid] - v;
        base[tid] = bexc;
        curs[tid * CPAD] = bexc;           // becomes the placement cursor
    }
    if (tid == NBUCK - 1) base[NBUCK] = s[tid];   // == EE
    if (tid == 0) rowp[NN] = EE;
}

// ---------------- partition: place (src,dst) bucket-contiguously ----------------
__global__ __launch_bounds__(256, 1) void k_partition(
    const int* __restrict__ eidx, int* __restrict__ curs, int2* __restrict__ pe2)
{
    __shared__ int cnt[NBUCK];
    __shared__ int start[NBUCK];
    int tid = threadIdx.x;
    int b = blockIdx.x;
    for (int i = tid; i < NBUCK; i += 256) cnt[i] = 0;
    __syncthreads();

    const int4v* src4 = (const int4v*)eidx;
    const int4v* dst4 = (const int4v*)(eidx + EE);
    int i0 = b << 10;                       // 1024 int4 per block
    int i1 = i0 + 1024; if (i1 > NE4) i1 = NE4;

    for (int i = i0 + tid; i < i1; i += 256) {
        int4v d = dst4[i];
        atomicAdd(&cnt[d.x >> 7], 1);
        atomicAdd(&cnt[d.y >> 7], 1);
        atomicAdd(&cnt[d.z >> 7], 1);
        atomicAdd(&cnt[d.w >> 7], 1);
    }
    __syncthreads();
    for (int i = tid; i < NBUCK; i += 256) {
        int c = cnt[i];
        start[i] = c ? atomicAdd(&curs[i * CPAD], c) : 0;   // reserve range
    }
    __syncthreads();
    for (int i = tid; i < NBUCK; i += 256) cnt[i] = 0;
    __syncthreads();
    for (int i = i0 + tid; i < i1; i += 256) {
        int4v s = src4[i];
        int4v d = dst4[i];
        int bk, r;
        bk = d.x >> 7; r = atomicAdd(&cnt[bk], 1); pe2[start[bk] + r] = make_int2(s.x, d.x);
        bk = d.y >> 7; r = atomicAdd(&cnt[bk], 1); pe2[start[bk] + r] = make_int2(s.y, d.y);
        bk = d.z >> 7; r = atomicAdd(&cnt[bk], 1); pe2[start[bk] + r] = make_int2(s.z, d.z);
        bk = d.w >> 7; r = atomicAdd(&cnt[bk], 1); pe2[start[bk] + r] = make_int2(s.w, d.w);
    }
}

// ---------------- fused B: per-bucket CSR (blocks < NBUCK) | stats1 (512 blocks) ----------------
__global__ __launch_bounds__(256) void k_fusedB(
    const int* __restrict__ cbase, const int2* __restrict__ pe2,
    int* __restrict__ rowp, int* __restrict__ srcl,
    const float* __restrict__ emb, float* __restrict__ stats)
{
    __shared__ int cnt[128], sc[128], ex[128];
    __shared__ float ls[64];
    int tid = threadIdx.x;
    int b = blockIdx.x;
    if (b < NBUCK) {
        int beg = cbase[b], end = cbase[b + 1];
        if (tid < 128) cnt[tid] = 0;
        __syncthreads();
        for (int e = beg + tid; e < end; e += 256) {
            int2 p = pe2[e];
            atomicAdd(&cnt[p.y & 127], 1);
        }
        __syncthreads();
        if (tid < 128) sc[tid] = cnt[tid];
        __syncthreads();
        for (int off = 1; off < 128; off <<= 1) {
            int x = (tid >= off && tid < 128) ? sc[tid - off] : 0;
            __syncthreads();
            if (tid < 128) sc[tid] += x;
            __syncthreads();
        }
        if (tid < 128) {
            int e0 = sc[tid] - cnt[tid];
            ex[tid] = e0;
            int node = b * 128 + tid;
            if (node < NN) rowp[node] = beg + e0;
            cnt[tid] = 0;
        }
        __syncthreads();
        for (int e = beg + tid; e < end; e += 256) {
            int2 p = pe2[e];
            int dl = p.y & 127;
            int r = atomicAdd(&cnt[dl], 1);
            srcl[beg + ex[dl] + r] = p.x;
        }
        return;
    }
    // stats over emb
    if (tid < 64) ls[tid] = 0.0f;
    __syncthreads();
    int sb = b - NBUCK;                   // 0..511
    int idx = sb * 256 + tid;
    int stride = 512 * 256;
    int c = idx & 31;
    float sum = 0.0f, q = 0.0f;
    for (int i = idx; i < NN * 32; i += stride) {
        float v = emb[i];
        sum += v; q += v * v;
    }
    sum += __shfl_xor(sum, 32);
    q   += __shfl_xor(q, 32);
    if ((tid & 63) < 32) {
        atomicAdd(&ls[c], sum);
        atomicAdd(&ls[32 + c], q);
    }
    __syncthreads();
    if (tid < 64) atomicAdd(&stats[tid], ls[tid]);
}

// ---------------- fused C: pq (fold bn1 + Wmsg into P,Q) ----------------
__global__ __launch_bounds__(256, 1) void k_fusedC(
    const float* __restrict__ par, const float* __restrict__ stats,
    const float* __restrict__ emb, float* __restrict__ P, float* __restrict__ Q)
{
    __shared__ f4 sWP4[256], sWQ4[256];
    __shared__ f4 sbP4[8], sbQ4[8];
    __shared__ float ssc[32], ssh[32];
    int tid = threadIdx.x;
    int b = blockIdx.x;
    if (tid < 32) {
        float mu  = stats[tid] * (1.0f / NN);
        float var = stats[32 + tid] * (1.0f / NN) - mu * mu;
        float s   = par[O_GALL + tid] * rsqrtf(var + 1e-5f);
        ssc[tid] = s;
        ssh[tid] = par[O_BEALL + tid] - mu * s;
    }
    __syncthreads();
    {
        float* wp = (float*)sWP4;
        float* wq = (float*)sWQ4;
        for (int e = tid; e < 1024; e += 256) {
            int k = e >> 5;
            float w1 = par[O_WMSG + e];
            float w2 = par[O_WMSG + 1024 + e];
            wp[e] = ssc[k] * (w1 - w2);
            wq[e] = ssc[k] * w2;
        }
    }
    if (tid < 32) {
        float aP = par[O_BMSG + tid], aQ = 0.0f;
        for (int k = 0; k < 32; k++) {
            float w1 = par[O_WMSG + k*32 + tid];
            float w2 = par[O_WMSG + (k+32)*32 + tid];
            aP += ssh[k] * (w1 - w2);
            aQ += ssh[k] * w2;
        }
        ((float*)sbP4)[tid] = aP;
        ((float*)sbQ4)[tid] = aQ;
    }
    __syncthreads();

    int n = b * 256 + tid;
    if (n >= NN) return;

    const f4* er = (const f4*)(emb + (size_t)n * 32);
    f4 e[8];
    #pragma unroll
    for (int g = 0; g < 8; g++) e[g] = er[g];

    f4* pr = (f4*)(P + (size_t)n * 32);
    f4* qr = (f4*)(Q + (size_t)n * 32);
    #pragma unroll
    for (int cg = 0; cg < 8; cg++) {
        f4 aP = sbP4[cg];
        f4 aQ = sbQ4[cg];
        #pragma unroll
        for (int kg = 0; kg < 8; kg++) {
            #pragma unroll
            for (int k = 0; k < 4; k++) {
                float ek = e[kg][k];
                aP += ek * sWP4[(kg*4+k)*8 + cg];
                aQ += ek * sWQ4[(kg*4+k)*8 + cg];
            }
        }
        pr[cg] = aP;
        qr[cg] = aQ;
    }
}

// ---------------- gather-max: one wave per node (8 edge-slices x 8 channel-groups) ----------------
__global__ __launch_bounds__(256) void k_gather(
    const int* __restrict__ rowp, const int* __restrict__ srcl,
    const float* __restrict__ Q, const float* __restrict__ P,
    float* __restrict__ agg)
{
    int tid = threadIdx.x;
    int lane = tid & 63;
    int wave = tid >> 6;
    int n = blockIdx.x * 4 + wave;       // 25000 blocks x 4 waves = 100000
    int slice = lane >> 3;               // 0..7 edge slice
    int cg    = lane & 7;                // channel group
    int beg = rowp[n], end = rowp[n + 1];
    const f4* Q4 = (const f4*)Q;
    f4 m = {-INFINITY, -INFINITY, -INFINITY, -INFINITY};
    for (int e = beg + slice; e < end; e += 8) {
        int s = __builtin_nontemporal_load(&srcl[e]);
        f4 q = Q4[(size_t)s * 8 + cg];
        m.x = fmaxf(m.x, q.x); m.y = fmaxf(m.y, q.y);
        m.z = fmaxf(m.z, q.z); m.w = fmaxf(m.w, q.w);
    }
    #pragma unroll
    for (int off = 8; off < 64; off <<= 1) {
        m.x = fmaxf(m.x, __shfl_xor(m.x, off));
        m.y = fmaxf(m.y, __shfl_xor(m.y, off));
        m.z = fmaxf(m.z, __shfl_xor(m.z, off));
        m.w = fmaxf(m.w, __shfl_xor(m.w, off));
    }
    if (lane < 8) {
        f4 o;
        if (end > beg) {
            f4 p = ((const f4*)P)[(size_t)n * 8 + lane];
            o = m + p;
        } else {
            o = (f4){0.f, 0.f, 0.f, 0.f};
        }
        ((f4*)agg)[(size_t)n * 8 + lane] = o;
    }
}

// ---------------- stats2: per-channel sum & sumsq over agg ----------------
__global__ __launch_bounds__(256) void k_stats(const float* __restrict__ xin,
                                               float* __restrict__ outsums, int count)
{
    __shared__ float ls[64];
    int tid = threadIdx.x;
    if (tid < 64) ls[tid] = 0.0f;
    __syncthreads();
    int idx = blockIdx.x * 256 + tid;
    int stride = gridDim.x * 256;
    int c = idx & 31;
    float s = 0.0f, q = 0.0f;
    for (int i = idx; i < count; i += stride) {
        float v = xin[i];
        s += v; q += v * v;
    }
    s += __shfl_xor(s, 32);
    q += __shfl_xor(q, 32);
    if ((tid & 63) < 32) {
        atomicAdd(&ls[c], s);
        atomicAdd(&ls[32 + c], q);
    }
    __syncthreads();
    if (tid < 64) atomicAdd(&outsums[tid], ls[tid]);
}

// ---------------- output MLP (bn1 & bn2 scales built in-block) ----------------
__global__ __launch_bounds__(256, 1) void k_out(
    const float* __restrict__ emb, const float* __restrict__ agg,
    const float* __restrict__ par, const float* __restrict__ stats,
    const int* __restrict__ flag, void* __restrict__ out)
{
    __shared__ f4 sW14[128];    // [32][16]
    __shared__ f4 sb14[4], sW24[4];
    __shared__ f4 sc14[8], sh14[8], sc24[8], sh24[8];
    __shared__ float sb2s;
    int tid = threadIdx.x;
    {
        float* s = (float*)sW14;
        for (int i = tid; i < 512; i += 256) s[i] = par[O_WOUT1 + i];
    }
    if (tid < 16) {
        ((float*)sb14)[tid] = par[O_BOUT1 + tid];
        ((float*)sW24)[tid] = par[O_WOUT2 + tid];
    }
    if (tid < 32) {
        float mu  = stats[tid] * (1.0f / NN);
        float var = stats[32 + tid] * (1.0f / NN) - mu * mu;
        float s   = par[O_GALL + tid] * rsqrtf(var + 1e-5f);
        ((float*)sc14)[tid] = s;
        ((float*)sh14)[tid] = par[O_BEALL + tid] - mu * s;
        float mu2  = stats[64 + tid] * (1.0f / NN);
        float var2 = stats[96 + tid] * (1.0f / NN) - mu2 * mu2;
        float s2   = par[O_GCONV + tid] * rsqrtf(var2 + 1e-5f);
        ((float*)sc24)[tid] = s2;
        ((float*)sh24)[tid] = par[O_BECONV + tid] - mu2 * s2;
    }
    if (tid == 0) sb2s = par[O_BOUT2];
    __syncthreads();

    int n = blockIdx.x * 256 + tid;
    if (n >= NN) return;

    const f4* er = (const f4*)(emb + (size_t)n * 32);
    const f4* ar = (const f4*)(agg + (size_t)n * 32);
    f4 h[8];
    #pragma unroll
    for (int g = 0; g < 8; g++) {
        f4 ev = er[g];
        f4 av = ar[g];
        h[g] = ev * sc14[g] + sh14[g] + av * sc24[g] + sh24[g];
    }
    f4 o1[4];
    #pragma unroll
    for (int g = 0; g < 4; g++) {
        f4 acc = sb14[g];
        #pragma unroll
        for (int kg = 0; kg < 8; kg++) {
            #pragma unroll
            for (int k = 0; k < 4; k++)
                acc += h[kg][k] * sW14[(kg*4+k)*4 + g];
        }
        o1[g] = elu4(acc);
    }
    float acc = sb2s;
    #pragma unroll
    for (int g = 0; g < 4; g++) {
        f4 p = o1[g] * sW24[g];
        acc += p.x + p.y + p.z + p.w;
    }

    if (*flag) ((float*)out)[n] = acc;
    else       ((bf16_t*)out)[n] = __float2bfloat16(acc);
}

extern "C" void kernel_launch(void* const* d_in, const int* in_sizes, int n_in,
                              void* d_out, int out_size, void* d_ws, size_t ws_size,
                              hipStream_t stream)
{
    const void* x_cont = d_in[0];
    const int* x_cat = (const int*)d_in[1];
    const int* eidx  = (const int*)d_in[2];

    float* ws    = (float*)d_ws;
    float* par   = ws + PARB;
    float* emb   = ws + EMB;
    float* P     = ws + PBUF;
    float* Q     = ws + QBUF;
    float* agg   = ws + ABUF;
    int2*  pe2   = (int2*)(ws + ABUF);    // aliased: pe2 dead before agg written
    float* stats = ws + SOFF;
    int*   flag  = (int*)(stats + 128);
    int*   curs  = (int*)(ws + CURS);
    int*   base  = (int*)(ws + BASEO);
    int*   rowp  = (int*)(ws + ROWP);
    int*   srcl  = (int*)(ws + SRCL);

    k_detect<<<1, 64, 0, stream>>>((const unsigned short*)d_in[11], flag);

    InitArgs ia;
    for (int t = 0; t < 19; t++) ia.p[t] = d_in[4 + t];
    ia.flag = flag; ia.par = par; ia.curs = curs; ia.stats = stats;
    k_init<<<NB_SCAN, 256, 0, stream>>>(ia);

    k_fusedA<<<NCB + NB_SCAN, 256, 0, stream>>>(eidx, curs, x_cont, x_cat,
                                                par, flag, emb);
    k_scan782<<<1, 1024, 0, stream>>>(curs, base, rowp);
    k_partition<<<NPART, 256, 0, stream>>>(eidx, curs, pe2);
    k_fusedB<<<NBUCK + 512, 256, 0, stream>>>(base, pe2, rowp, srcl, emb, stats);
    k_fusedC<<<NB_SCAN, 256, 0, stream>>>(par, stats, emb, P, Q);
    k_gather<<<NN / 4, 256, 0, stream>>>(rowp, srcl, Q, P, agg);
    k_stats<<<512, 256, 0, stream>>>(agg, stats + 64, NN * 32);
    k_out<<<NB_SCAN, 256, 0, stream>>>(emb, agg, par, stats, flag, d_out);
}

// Round 2
// 294.490 us; speedup vs baseline: 1.3104x; 1.0697x over previous
//
#include <hip/hip_runtime.h>
#include <hip/hip_bf16.h>

#define NN 100000
#define EE 1600000
#define NB_SCAN 391   // ceil(NN/256)

// ---- bucketed CSR parameters ----
#define NBUCK 782     // dst>>7 -> 782 buckets of 128 nodes
#define CPAD  16      // cursor padding (64B) to kill line contention
#define NCB   128     // count blocks in fusedA
#define NPART 391     // partition blocks (4096 edges each)
#define NE4   400000  // EE/4
#define BCAP  2560    // LDS staging capacity per bucket (mean 2046, sd ~45 -> +11 sigma)

typedef __hip_bfloat16 bf16_t;
typedef int int4v __attribute__((ext_vector_type(4)));
typedef float f4 __attribute__((ext_vector_type(4)));

// ---- workspace layout (float offsets) ----
#define PARB  600000       // params fp32            4465
#define EMB   604480       // N*32 raw (pre-bn1) embeddings
#define PBUF  3804480      // N*32  P' (bn1+Wmsg folded)
#define QBUF  7004480      // N*32  Q  (bn1+Wmsg folded)
#define ABUF  10204480     // N*32  agg; ALSO aliased as packed pe[EE] before k_gather
#define SOFF  13404480     // stats: [0:32) sum1 [32:64) sq1 [64:96) sum2 [96:128) sq2, [128] flag
#define CURS  (SOFF + 256)           // NBUCK*CPAD ints (padded bucket counters/cursors)
#define BASEO (CURS + 12512)         // NBUCK+1 ints (bucket bases)
#define ROWP  (BASEO + 1024)         // 100001 ints
#define SRCL  (ROWP + 100002)        // 1600000 ints

// ---- param offsets inside PARB ----
#define O_WCONT 0
#define O_BCONT 96
#define O_TCHRG 112
#define O_TPDG  136
#define O_TPV   192
#define O_WCAT  256
#define O_BCAT  640
#define O_WENC  656
#define O_BENC  1680
#define O_GALL  1712
#define O_BEALL 1744
#define O_WMSG  1776
#define O_BMSG  3824
#define O_GCONV 3856
#define O_BECONV 3888
#define O_WOUT1 3920
#define O_BOUT1 4432
#define O_WOUT2 4448
#define O_BOUT2 4464
#define NPAR    4465

__device__ __forceinline__ float bf(unsigned short u) {
    return __uint_as_float(((unsigned)u) << 16);
}
__device__ __forceinline__ f4 elu4(f4 v) {
    f4 r;
    r.x = v.x > 0.0f ? v.x : expm1f(v.x);
    r.y = v.y > 0.0f ? v.y : expm1f(v.y);
    r.z = v.z > 0.0f ? v.z : expm1f(v.z);
    r.w = v.w > 0.0f ? v.w : expm1f(v.w);
    return r;
}
__device__ __forceinline__ f4 f4max(f4 a, f4 b) {
    f4 r;
    r.x = fmaxf(a.x, b.x); r.y = fmaxf(a.y, b.y);
    r.z = fmaxf(a.z, b.z); r.w = fmaxf(a.w, b.w);
    return r;
}

// ---------------- init: zero cursors & stats; block 0 detects dtype + converts params ----------------
struct InitArgs {
    const void* p[19];
    const unsigned short* wdet;   // d_in[11] (W_enc) raw, for dtype sniffing
    int*        flagw;
    float*      par;
    int*        curs;
    float*      stats;
};

__global__ __launch_bounds__(256) void k_init(InitArgs a)
{
    const int offs[20] = {O_WCONT,O_BCONT,O_TCHRG,O_TPDG,O_TPV,O_WCAT,O_BCAT,O_WENC,
                          O_BENC,O_GALL,O_BEALL,O_WMSG,O_BMSG,O_GCONV,O_BECONV,
                          O_WOUT1,O_BOUT1,O_WOUT2,O_BOUT2,NPAR};
    __shared__ int sflag;
    int b = blockIdx.x, tid = threadIdx.x;
    int g = b * 256 + tid;
    if (g < NBUCK * CPAD) a.curs[g] = 0;
    if (g < 128) a.stats[g] = 0.0f;
    if (b == 0) {
        if (tid == 0) sflag = 0;
        __syncthreads();
        int bad = 0;
        for (int i = tid; i < 1024; i += 256) {
            unsigned e = (a.wdet[i] >> 7) & 0xFFu;
            if (e >= 137u) bad = 1;       // |v| >= 2^10 as bf16 -> impossible for real weights
        }
        if (bad) atomicOr(&sflag, 1);
        __syncthreads();
        int f32 = sflag;
        if (tid == 0) *a.flagw = f32;
        for (int i = tid; i < NPAR; i += 256) {
            int t = 0;
            while (offs[t + 1] <= i) t++;
            int l = i - offs[t];
            const void* s = a.p[t];
            a.par[i] = f32 ? ((const float*)s)[l] : bf(((const unsigned short*)s)[l]);
        }
    }
}

// ---------------- fused A: bucket-count (blocks < NCB) | embed (blocks >= NCB) ----------------
__global__ __launch_bounds__(256, 1) void k_fusedA(
    const int* __restrict__ eidx, int* __restrict__ curs,
    const void* __restrict__ xc, const int* __restrict__ x_cat,
    const float* __restrict__ par, const int* __restrict__ flag,
    float* __restrict__ emb)
{
    __shared__ f4 sWc4[24];     // W_cont [6][16]
    __shared__ f4 sbc4[4];
    __shared__ f4 sTc4[6], sTp4[14], sTv4[16];
    __shared__ f4 sWcat4[96];   // [24][16]
    __shared__ f4 sbcat4[4];
    __shared__ f4 sWe4[256];    // [32][32]
    __shared__ f4 sbe4[8];
    int tid = threadIdx.x;
    int b = blockIdx.x;

    if (b < NCB) {
        // ---- LDS-private bucket histogram of dst>>7 ----
        __shared__ int cnt[NBUCK];
        for (int i = tid; i < NBUCK; i += 256) cnt[i] = 0;
        __syncthreads();
        const int4v* dst4 = (const int4v*)(eidx + EE);
        int i0 = b * (NE4 / NCB);          // 3125 int4 per block
        int i1 = i0 + (NE4 / NCB);
        for (int i = i0 + tid; i < i1; i += 256) {
            int4v d = __builtin_nontemporal_load(&dst4[i]);
            atomicAdd(&cnt[d.x >> 7], 1);
            atomicAdd(&cnt[d.y >> 7], 1);
            atomicAdd(&cnt[d.z >> 7], 1);
            atomicAdd(&cnt[d.w >> 7], 1);
        }
        __syncthreads();
        for (int i = tid; i < NBUCK; i += 256) {
            int c = cnt[i];
            if (c) atomicAdd(&curs[i * CPAD], c);   // no-return, padded
        }
        return;
    }

    // ---- embed path ----
    {
        float* s;
        s=(float*)sWc4;   for(int i=tid;i<96;  i+=256) s[i]=par[O_WCONT+i];
        s=(float*)sbc4;   for(int i=tid;i<16;  i+=256) s[i]=par[O_BCONT+i];
        s=(float*)sTc4;   for(int i=tid;i<24;  i+=256) s[i]=par[O_TCHRG+i];
        s=(float*)sTp4;   for(int i=tid;i<56;  i+=256) s[i]=par[O_TPDG+i];
        s=(float*)sTv4;   for(int i=tid;i<64;  i+=256) s[i]=par[O_TPV+i];
        s=(float*)sWcat4; for(int i=tid;i<384; i+=256) s[i]=par[O_WCAT+i];
        s=(float*)sbcat4; for(int i=tid;i<16;  i+=256) s[i]=par[O_BCAT+i];
        s=(float*)sWe4;   for(int i=tid;i<1024;i+=256) s[i]=par[O_WENC+i];
        s=(float*)sbe4;   for(int i=tid;i<32;  i+=256) s[i]=par[O_BENC+i];
    }
    __syncthreads();

    int n = (b - NCB) * 256 + tid;
    if (n >= NN) return;

    float x0,x1,x2,x3,x4,x5;
    if (*flag) {
        const float* xr = (const float*)xc + (size_t)n * 6;
        x0=xr[0]; x1=xr[1]; x2=xr[2]; x3=xr[3]; x4=xr[4]; x5=xr[5];
    } else {
        const unsigned* xr = (const unsigned*)xc + (size_t)n * 3;
        unsigned w0=xr[0], w1=xr[1], w2=xr[2];
        x0=__uint_as_float(w0<<16); x1=__uint_as_float(w0 & 0xFFFF0000u);
        x2=__uint_as_float(w1<<16); x3=__uint_as_float(w1 & 0xFFFF0000u);
        x4=__uint_as_float(w2<<16); x5=__uint_as_float(w2 & 0xFFFF0000u);
    }

    f4 ec[4];
    #pragma unroll
    for (int g = 0; g < 4; g++) {
        f4 a = sbc4[g];
        a += x0 * sWc4[0*4+g]; a += x1 * sWc4[1*4+g]; a += x2 * sWc4[2*4+g];
        a += x3 * sWc4[3*4+g]; a += x4 * sWc4[4*4+g]; a += x5 * sWc4[5*4+g];
        ec[g] = elu4(a);
    }

    int c0 = x_cat[n*3+0], c1 = x_cat[n*3+1], c2 = x_cat[n*3+2];
    int a0 = c0 < 0 ? -c0 : c0;
    int pi = (a0==1)?0:(a0==2)?1:(a0==11)?2:(a0==13)?3:(a0==22)?4:(a0==130)?5:6;
    int ci = c1 + 1;

    f4 t0a = sTc4[ci*2],  t0b = sTc4[ci*2+1];
    f4 t1a = sTp4[pi*2],  t1b = sTp4[pi*2+1];
    f4 t2a = sTv4[c2*2],  t2b = sTv4[c2*2+1];

    f4 ecat[4];
    #pragma unroll
    for (int g = 0; g < 4; g++) {
        f4 a = sbcat4[g];
        #pragma unroll
        for (int k = 0; k < 4; k++) a += t0a[k] * sWcat4[(k     )*4+g];
        #pragma unroll
        for (int k = 0; k < 4; k++) a += t0b[k] * sWcat4[(4 + k )*4+g];
        #pragma unroll
        for (int k = 0; k < 4; k++) a += t1a[k] * sWcat4[(8 + k )*4+g];
        #pragma unroll
        for (int k = 0; k < 4; k++) a += t1b[k] * sWcat4[(12 + k)*4+g];
        #pragma unroll
        for (int k = 0; k < 4; k++) a += t2a[k] * sWcat4[(16 + k)*4+g];
        #pragma unroll
        for (int k = 0; k < 4; k++) a += t2b[k] * sWcat4[(20 + k)*4+g];
        ecat[g] = elu4(a);
    }

    f4* o = (f4*)(emb + (size_t)n * 32);
    #pragma unroll
    for (int cg = 0; cg < 8; cg++) {
        f4 a = sbe4[cg];
        #pragma unroll
        for (int kg = 0; kg < 4; kg++) {
            #pragma unroll
            for (int k = 0; k < 4; k++)
                a += ecat[kg][k] * sWe4[(kg*4+k)*8 + cg];
        }
        #pragma unroll
        for (int kg = 0; kg < 4; kg++) {
            #pragma unroll
            for (int k = 0; k < 4; k++)
                a += ec[kg][k] * sWe4[(16 + kg*4+k)*8 + cg];
        }
        o[cg] = elu4(a);
    }
}

// ---------------- scan of 782 bucket counts -> bases; cursors := base ----------------
__global__ __launch_bounds__(1024) void k_scan782(int* __restrict__ curs,
                                                  int* __restrict__ base,
                                                  int* __restrict__ rowp)
{
    __shared__ int s[1024];
    int tid = threadIdx.x;
    int v = (tid < NBUCK) ? curs[tid * CPAD] : 0;
    s[tid] = v;
    __syncthreads();
    for (int off = 1; off < 1024; off <<= 1) {
        int x = (tid >= off) ? s[tid - off] : 0;
        __syncthreads();
        s[tid] += x;
        __syncthreads();
    }
    if (tid < NBUCK) {
        int bexc = s[tid] - v;
        base[tid] = bexc;
        curs[tid * CPAD] = bexc;           // becomes the placement cursor
    }
    if (tid == NBUCK - 1) base[NBUCK] = s[tid];   // == EE
    if (tid == 0) rowp[NN] = EE;
}

// ---------------- partition: place packed (src<<7)|(dst&127) bucket-contiguously ----------------
__global__ __launch_bounds__(256, 1) void k_partition(
    const int* __restrict__ eidx, int* __restrict__ curs, int* __restrict__ pe)
{
    __shared__ int cnt[NBUCK];
    __shared__ int start[NBUCK];
    int tid = threadIdx.x;
    int b = blockIdx.x;
    for (int i = tid; i < NBUCK; i += 256) cnt[i] = 0;
    __syncthreads();

    const int4v* src4 = (const int4v*)eidx;
    const int4v* dst4 = (const int4v*)(eidx + EE);
    int i0 = b << 10;                       // 1024 int4 per block
    int i1 = i0 + 1024; if (i1 > NE4) i1 = NE4;

    for (int i = i0 + tid; i < i1; i += 256) {
        int4v d = dst4[i];
        atomicAdd(&cnt[d.x >> 7], 1);
        atomicAdd(&cnt[d.y >> 7], 1);
        atomicAdd(&cnt[d.z >> 7], 1);
        atomicAdd(&cnt[d.w >> 7], 1);
    }
    __syncthreads();
    for (int i = tid; i < NBUCK; i += 256) {
        int c = cnt[i];
        start[i] = c ? atomicAdd(&curs[i * CPAD], c) : 0;   // reserve range
    }
    __syncthreads();
    for (int i = tid; i < NBUCK; i += 256) cnt[i] = 0;
    __syncthreads();
    for (int i = i0 + tid; i < i1; i += 256) {
        int4v s = src4[i];
        int4v d = dst4[i];
        int bk, r;
        bk = d.x >> 7; r = atomicAdd(&cnt[bk], 1); pe[start[bk] + r] = (s.x << 7) | (d.x & 127);
        bk = d.y >> 7; r = atomicAdd(&cnt[bk], 1); pe[start[bk] + r] = (s.y << 7) | (d.y & 127);
        bk = d.z >> 7; r = atomicAdd(&cnt[bk], 1); pe[start[bk] + r] = (s.z << 7) | (d.z & 127);
        bk = d.w >> 7; r = atomicAdd(&cnt[bk], 1); pe[start[bk] + r] = (s.w << 7) | (d.w & 127);
    }
}

// ---------------- fused B: per-bucket CSR, single global pass via LDS staging
//                  (blocks < NBUCK) | stats1 (512 blocks) ----------------
__global__ __launch_bounds__(256) void k_fusedB(
    const int* __restrict__ cbase, const int* __restrict__ pe,
    int* __restrict__ rowp, int* __restrict__ srcl,
    const float* __restrict__ emb, float* __restrict__ stats)
{
    __shared__ int stage[BCAP];      // 10 KB
    __shared__ int cnt[128], sc[128], ex[128];
    __shared__ float ls[64];
    int tid = threadIdx.x;
    int b = blockIdx.x;
    if (b < NBUCK) {
        int beg = cbase[b], end = cbase[b + 1];
        int m = end - beg;
        if (tid < 128) cnt[tid] = 0;
        __syncthreads();
        for (int i = tid; i < m; i += 256) {
            int p = pe[beg + i];
            if (i < BCAP) stage[i] = p;
            atomicAdd(&cnt[p & 127], 1);
        }
        __syncthreads();
        if (tid < 128) sc[tid] = cnt[tid];
        __syncthreads();
        for (int off = 1; off < 128; off <<= 1) {
            int x = (tid >= off && tid < 128) ? sc[tid - off] : 0;
            __syncthreads();
            if (tid < 128) sc[tid] += x;
            __syncthreads();
        }
        if (tid < 128) {
            int e0 = sc[tid] - cnt[tid];
            ex[tid] = e0;
            int node = b * 128 + tid;
            if (node < NN) rowp[node] = beg + e0;
            cnt[tid] = 0;
        }
        __syncthreads();
        for (int i = tid; i < m; i += 256) {
            int p = (i < BCAP) ? stage[i] : pe[beg + i];
            int dl = p & 127;
            int r = atomicAdd(&cnt[dl], 1);
            srcl[beg + ex[dl] + r] = p >> 7;
        }
        return;
    }
    // stats over emb
    if (tid < 64) ls[tid] = 0.0f;
    __syncthreads();
    int sb = b - NBUCK;                   // 0..511
    int idx = sb * 256 + tid;
    int stride = 512 * 256;
    int c = idx & 31;
    float sum = 0.0f, q = 0.0f;
    for (int i = idx; i < NN * 32; i += stride) {
        float v = emb[i];
        sum += v; q += v * v;
    }
    sum += __shfl_xor(sum, 32);
    q   += __shfl_xor(q, 32);
    if ((tid & 63) < 32) {
        atomicAdd(&ls[c], sum);
        atomicAdd(&ls[32 + c], q);
    }
    __syncthreads();
    if (tid < 64) atomicAdd(&stats[tid], ls[tid]);
}

// ---------------- fused C: pq (fold bn1 + Wmsg into P,Q) ----------------
__global__ __launch_bounds__(256, 1) void k_fusedC(
    const float* __restrict__ par, const float* __restrict__ stats,
    const float* __restrict__ emb, float* __restrict__ P, float* __restrict__ Q)
{
    __shared__ f4 sWP4[256], sWQ4[256];
    __shared__ f4 sbP4[8], sbQ4[8];
    __shared__ float ssc[32], ssh[32];
    int tid = threadIdx.x;
    int b = blockIdx.x;
    if (tid < 32) {
        float mu  = stats[tid] * (1.0f / NN);
        float var = stats[32 + tid] * (1.0f / NN) - mu * mu;
        float s   = par[O_GALL + tid] * rsqrtf(var + 1e-5f);
        ssc[tid] = s;
        ssh[tid] = par[O_BEALL + tid] - mu * s;
    }
    __syncthreads();
    {
        float* wp = (float*)sWP4;
        float* wq = (float*)sWQ4;
        for (int e = tid; e < 1024; e += 256) {
            int k = e >> 5;
            float w1 = par[O_WMSG + e];
            float w2 = par[O_WMSG + 1024 + e];
            wp[e] = ssc[k] * (w1 - w2);
            wq[e] = ssc[k] * w2;
        }
    }
    if (tid < 32) {
        float aP = par[O_BMSG + tid], aQ = 0.0f;
        for (int k = 0; k < 32; k++) {
            float w1 = par[O_WMSG + k*32 + tid];
            float w2 = par[O_WMSG + (k+32)*32 + tid];
            aP += ssh[k] * (w1 - w2);
            aQ += ssh[k] * w2;
        }
        ((float*)sbP4)[tid] = aP;
        ((float*)sbQ4)[tid] = aQ;
    }
    __syncthreads();

    int n = b * 256 + tid;
    if (n >= NN) return;

    const f4* er = (const f4*)(emb + (size_t)n * 32);
    f4 e[8];
    #pragma unroll
    for (int g = 0; g < 8; g++) e[g] = er[g];

    f4* pr = (f4*)(P + (size_t)n * 32);
    f4* qr = (f4*)(Q + (size_t)n * 32);
    #pragma unroll
    for (int cg = 0; cg < 8; cg++) {
        f4 aP = sbP4[cg];
        f4 aQ = sbQ4[cg];
        #pragma unroll
        for (int kg = 0; kg < 8; kg++) {
            #pragma unroll
            for (int k = 0; k < 4; k++) {
                float ek = e[kg][k];
                aP += ek * sWP4[(kg*4+k)*8 + cg];
                aQ += ek * sWQ4[(kg*4+k)*8 + cg];
            }
        }
        pr[cg] = aP;
        qr[cg] = aQ;
    }
}

// ---------------- gather-max: one wave per node; 4-slot batched loads for MLP ----------------
__global__ __launch_bounds__(256) void k_gather(
    const int* __restrict__ rowp, const int* __restrict__ srcl,
    const float* __restrict__ Q, const float* __restrict__ P,
    float* __restrict__ agg)
{
    int tid = threadIdx.x;
    int lane = tid & 63;
    int wave = tid >> 6;
    int n = blockIdx.x * 4 + wave;       // 25000 blocks x 4 waves = 100000
    int slice = lane >> 3;               // 0..7 edge slice
    int cg    = lane & 7;                // channel group
    int beg = rowp[n], end = rowp[n + 1];
    const f4* Q4 = (const f4*)Q;

    // hoisted P read (independent of the edge loop)
    f4 pv = (f4){0.f, 0.f, 0.f, 0.f};
    if (lane < 8 && end > beg) pv = ((const f4*)P)[(size_t)n * 8 + lane];

    f4 m = {-INFINITY, -INFINITY, -INFINITY, -INFINITY};
    // 4 edge-slots per lane per iteration; clamped dup indices are harmless under max
    for (int e = beg + slice; e < end; e += 32) {
        int e1 = min(e + 8,  end - 1);
        int e2 = min(e + 16, end - 1);
        int e3 = min(e + 24, end - 1);
        int s0 = __builtin_nontemporal_load(&srcl[e]);
        int s1 = __builtin_nontemporal_load(&srcl[e1]);
        int s2 = __builtin_nontemporal_load(&srcl[e2]);
        int s3 = __builtin_nontemporal_load(&srcl[e3]);
        f4 q0 = Q4[(size_t)s0 * 8 + cg];
        f4 q1 = Q4[(size_t)s1 * 8 + cg];
        f4 q2 = Q4[(size_t)s2 * 8 + cg];
        f4 q3 = Q4[(size_t)s3 * 8 + cg];
        q0 = f4max(q0, q1);
        q2 = f4max(q2, q3);
        m = f4max(m, f4max(q0, q2));
    }
    #pragma unroll
    for (int off = 8; off < 64; off <<= 1) {
        m.x = fmaxf(m.x, __shfl_xor(m.x, off));
        m.y = fmaxf(m.y, __shfl_xor(m.y, off));
        m.z = fmaxf(m.z, __shfl_xor(m.z, off));
        m.w = fmaxf(m.w, __shfl_xor(m.w, off));
    }
    if (lane < 8) {
        f4 o;
        if (end > beg) o = m + pv;
        else           o = (f4){0.f, 0.f, 0.f, 0.f};
        ((f4*)agg)[(size_t)n * 8 + lane] = o;
    }
}

// ---------------- stats2: per-channel sum & sumsq over agg ----------------
__global__ __launch_bounds__(256) void k_stats(const float* __restrict__ xin,
                                               float* __restrict__ outsums, int count)
{
    __shared__ float ls[64];
    int tid = threadIdx.x;
    if (tid < 64) ls[tid] = 0.0f;
    __syncthreads();
    int idx = blockIdx.x * 256 + tid;
    int stride = gridDim.x * 256;
    int c = idx & 31;
    float s = 0.0f, q = 0.0f;
    for (int i = idx; i < count; i += stride) {
        float v = xin[i];
        s += v; q += v * v;
    }
    s += __shfl_xor(s, 32);
    q += __shfl_xor(q, 32);
    if ((tid & 63) < 32) {
        atomicAdd(&ls[c], s);
        atomicAdd(&ls[32 + c], q);
    }
    __syncthreads();
    if (tid < 64) atomicAdd(&outsums[tid], ls[tid]);
}

// ---------------- output MLP (bn1 & bn2 scales built in-block) ----------------
__global__ __launch_bounds__(256, 1) void k_out(
    const float* __restrict__ emb, const float* __restrict__ agg,
    const float* __restrict__ par, const float* __restrict__ stats,
    const int* __restrict__ flag, void* __restrict__ out)
{
    __shared__ f4 sW14[128];    // [32][16]
    __shared__ f4 sb14[4], sW24[4];
    __shared__ f4 sc14[8], sh14[8], sc24[8], sh24[8];
    __shared__ float sb2s;
    int tid = threadIdx.x;
    {
        float* s = (float*)sW14;
        for (int i = tid; i < 512; i += 256) s[i] = par[O_WOUT1 + i];
    }
    if (tid < 16) {
        ((float*)sb14)[tid] = par[O_BOUT1 + tid];
        ((float*)sW24)[tid] = par[O_WOUT2 + tid];
    }
    if (tid < 32) {
        float mu  = stats[tid] * (1.0f / NN);
        float var = stats[32 + tid] * (1.0f / NN) - mu * mu;
        float s   = par[O_GALL + tid] * rsqrtf(var + 1e-5f);
        ((float*)sc14)[tid] = s;
        ((float*)sh14)[tid] = par[O_BEALL + tid] - mu * s;
        float mu2  = stats[64 + tid] * (1.0f / NN);
        float var2 = stats[96 + tid] * (1.0f / NN) - mu2 * mu2;
        float s2   = par[O_GCONV + tid] * rsqrtf(var2 + 1e-5f);
        ((float*)sc24)[tid] = s2;
        ((float*)sh24)[tid] = par[O_BECONV + tid] - mu2 * s2;
    }
    if (tid == 0) sb2s = par[O_BOUT2];
    __syncthreads();

    int n = blockIdx.x * 256 + tid;
    if (n >= NN) return;

    const f4* er = (const f4*)(emb + (size_t)n * 32);
    const f4* ar = (const f4*)(agg + (size_t)n * 32);
    f4 h[8];
    #pragma unroll
    for (int g = 0; g < 8; g++) {
        f4 ev = er[g];
        f4 av = ar[g];
        h[g] = ev * sc14[g] + sh14[g] + av * sc24[g] + sh24[g];
    }
    f4 o1[4];
    #pragma unroll
    for (int g = 0; g < 4; g++) {
        f4 acc = sb14[g];
        #pragma unroll
        for (int kg = 0; kg < 8; kg++) {
            #pragma unroll
            for (int k = 0; k < 4; k++)
                acc += h[kg][k] * sW14[(kg*4+k)*4 + g];
        }
        o1[g] = elu4(acc);
    }
    float acc = sb2s;
    #pragma unroll
    for (int g = 0; g < 4; g++) {
        f4 p = o1[g] * sW24[g];
        acc += p.x + p.y + p.z + p.w;
    }

    if (*flag) ((float*)out)[n] = acc;
    else       ((bf16_t*)out)[n] = __float2bfloat16(acc);
}

extern "C" void kernel_launch(void* const* d_in, const int* in_sizes, int n_in,
                              void* d_out, int out_size, void* d_ws, size_t ws_size,
                              hipStream_t stream)
{
    const void* x_cont = d_in[0];
    const int* x_cat = (const int*)d_in[1];
    const int* eidx  = (const int*)d_in[2];

    float* ws    = (float*)d_ws;
    float* par   = ws + PARB;
    float* emb   = ws + EMB;
    float* P     = ws + PBUF;
    float* Q     = ws + QBUF;
    float* agg   = ws + ABUF;
    int*   pe    = (int*)(ws + ABUF);     // aliased: packed edges dead before agg written
    float* stats = ws + SOFF;
    int*   flag  = (int*)(stats + 128);
    int*   curs  = (int*)(ws + CURS);
    int*   base  = (int*)(ws + BASEO);
    int*   rowp  = (int*)(ws + ROWP);
    int*   srcl  = (int*)(ws + SRCL);

    InitArgs ia;
    for (int t = 0; t < 19; t++) ia.p[t] = d_in[4 + t];
    ia.wdet = (const unsigned short*)d_in[11];
    ia.flagw = flag; ia.par = par; ia.curs = curs; ia.stats = stats;
    k_init<<<NB_SCAN, 256, 0, stream>>>(ia);

    k_fusedA<<<NCB + NB_SCAN, 256, 0, stream>>>(eidx, curs, x_cont, x_cat,
                                                par, flag, emb);
    k_scan782<<<1, 1024, 0, stream>>>(curs, base, rowp);
    k_partition<<<NPART, 256, 0, stream>>>(eidx, curs, pe);
    k_fusedB<<<NBUCK + 512, 256, 0, stream>>>(base, pe, rowp, srcl, emb, stats);
    k_fusedC<<<NB_SCAN, 256, 0, stream>>>(par, stats, emb, P, Q);
    k_gather<<<NN / 4, 256, 0, stream>>>(rowp, srcl, Q, P, agg);
    k_stats<<<512, 256, 0, stream>>>(agg, stats + 64, NN * 32);
    k_out<<<NB_SCAN, 256, 0, stream>>>(emb, agg, par, stats, flag, d_out);
}

// Round 3
// 291.813 us; speedup vs baseline: 1.3224x; 1.0092x over previous
//
#include <hip/hip_runtime.h>
#include <hip/hip_bf16.h>
#include <hip/hip_cooperative_groups.h>

namespace cg = cooperative_groups;

#define NN 100000
#define EE 1600000
#define NB_SCAN 391   // ceil(NN/256)

// ---- bucketed CSR parameters ----
#define NBUCK 782     // dst>>7 -> 782 buckets of 128 nodes
#define CPAD  16      // cursor padding (64B) to kill line contention
#define NCB   128     // count blocks
#define NPART 391     // partition chunks (4096 edges each)
#define NE4   400000  // EE/4
#define BCAP  2560    // LDS staging capacity per bucket

typedef __hip_bfloat16 bf16_t;
typedef int int4v __attribute__((ext_vector_type(4)));
typedef float f4 __attribute__((ext_vector_type(4)));

// ---- workspace layout (float offsets) ----
#define PARB  600000
#define EMB   604480
#define PBUF  3804480
#define QBUF  7004480
#define ABUF  10204480     // agg; aliased as packed pe[EE] before gather
#define SOFF  13404480     // stats: [0:32) sum1 [32:64) sq1 [64:96) sum2 [96:128) sq2, [128] flag
#define CURS  (SOFF + 256)
#define BASEO (CURS + 12512)
#define ROWP  (BASEO + 1024)
#define SRCL  (ROWP + 100002)

// ---- param offsets inside PARB ----
#define O_WCONT 0
#define O_BCONT 96
#define O_TCHRG 112
#define O_TPDG  136
#define O_TPV   192
#define O_WCAT  256
#define O_BCAT  640
#define O_WENC  656
#define O_BENC  1680
#define O_GALL  1712
#define O_BEALL 1744
#define O_WMSG  1776
#define O_BMSG  3824
#define O_GCONV 3856
#define O_BECONV 3888
#define O_WOUT1 3920
#define O_BOUT1 4432
#define O_WOUT2 4448
#define O_BOUT2 4464
#define NPAR    4465

__device__ __forceinline__ float bf(unsigned short u) {
    return __uint_as_float(((unsigned)u) << 16);
}
__device__ __forceinline__ f4 elu4(f4 v) {
    f4 r;
    r.x = v.x > 0.0f ? v.x : expm1f(v.x);
    r.y = v.y > 0.0f ? v.y : expm1f(v.y);
    r.z = v.z > 0.0f ? v.z : expm1f(v.z);
    r.w = v.w > 0.0f ? v.w : expm1f(v.w);
    return r;
}
__device__ __forceinline__ f4 f4max(f4 a, f4 b) {
    f4 r;
    r.x = fmaxf(a.x, b.x); r.y = fmaxf(a.y, b.y);
    r.z = fmaxf(a.z, b.z); r.w = fmaxf(a.w, b.w);
    return r;
}

// ======================= MEGA KERNEL (cooperative) =======================

struct MegaArgs {
    const void* p[19];
    const unsigned short* wdet;
    const int* eidx;
    const void* xc;
    const int* xcat;
    float* par;
    int*   flagw;
    int*   curs;
    float* stats;
    int*   base;
    int*   rowp;
    int*   srcl;
    int*   pe;
    float* emb;
    float* P;
    float* Q;
    float* agg;
    void*  out;
};

struct SMemEmb { float wc[96], bc[16], tc[24], tp[56], tv[64], wcat[384], bcat[16], we[1024], be[32]; };
struct SMemScan { int t[256]; };
struct SMemPart { int cnt[NBUCK]; int start[NBUCK]; };
struct SMemCsr  { int stage[BCAP]; int cnt[128]; int sc[128]; int ex[128]; };
struct SMemPq   { float wp[1024], wq[1024], bp[32], bq[32], ssc[32], ssh[32]; };
struct SMemSt   { float ls[64]; };
struct SMemOut  { float w1[512], b1[16], w2[16], sc1[32], sh1[32], sc2[32], sh2[32], b2s; };
union SMemU {
    SMemEmb  emb;
    SMemScan scan;
    int      cnt782[NBUCK];
    SMemPart part;
    SMemCsr  csr;
    SMemPq   pq;
    SMemSt   st;
    SMemOut  outp;
};

__global__ __launch_bounds__(256, 4) void k_mega(MegaArgs a)
{
    __shared__ alignas(16) SMemU sm;
    cg::grid_group gg = cg::this_grid();
    const int tid = threadIdx.x;
    const int b   = blockIdx.x;
    const int G   = gridDim.x;

    // ================= P0: init (zero cursors/stats; block 0: detect + params) =================
    {
        int g = b * 256 + tid;
        for (int i = g; i < NBUCK * CPAD; i += G * 256) a.curs[i] = 0;
        if (g < 128) a.stats[g] = 0.0f;
        if (b == 0) {
            const int offs[20] = {O_WCONT,O_BCONT,O_TCHRG,O_TPDG,O_TPV,O_WCAT,O_BCAT,O_WENC,
                                  O_BENC,O_GALL,O_BEALL,O_WMSG,O_BMSG,O_GCONV,O_BECONV,
                                  O_WOUT1,O_BOUT1,O_WOUT2,O_BOUT2,NPAR};
            if (tid == 0) sm.scan.t[0] = 0;
            __syncthreads();
            int bad = 0;
            for (int i = tid; i < 1024; i += 256) {
                unsigned e = (a.wdet[i] >> 7) & 0xFFu;
                if (e >= 137u) bad = 1;
            }
            if (bad) atomicOr(&sm.scan.t[0], 1);
            __syncthreads();
            int f32 = sm.scan.t[0];
            if (tid == 0) *a.flagw = f32;
            for (int i = tid; i < NPAR; i += 256) {
                int t = 0;
                while (offs[t + 1] <= i) t++;
                int l = i - offs[t];
                const void* s = a.p[t];
                a.par[i] = f32 ? ((const float*)s)[l] : bf(((const unsigned short*)s)[l]);
            }
        }
    }
    gg.sync();

    // ================= P1: bucket-count (391..518) | embed (0..390) =================
    if (b < NB_SCAN) {
        const float* par = a.par;
        float* s;
        s=sm.emb.wc;   for(int i=tid;i<96;  i+=256) s[i]=par[O_WCONT+i];
        s=sm.emb.bc;   for(int i=tid;i<16;  i+=256) s[i]=par[O_BCONT+i];
        s=sm.emb.tc;   for(int i=tid;i<24;  i+=256) s[i]=par[O_TCHRG+i];
        s=sm.emb.tp;   for(int i=tid;i<56;  i+=256) s[i]=par[O_TPDG+i];
        s=sm.emb.tv;   for(int i=tid;i<64;  i+=256) s[i]=par[O_TPV+i];
        s=sm.emb.wcat; for(int i=tid;i<384; i+=256) s[i]=par[O_WCAT+i];
        s=sm.emb.bcat; for(int i=tid;i<16;  i+=256) s[i]=par[O_BCAT+i];
        s=sm.emb.we;   for(int i=tid;i<1024;i+=256) s[i]=par[O_WENC+i];
        s=sm.emb.be;   for(int i=tid;i<32;  i+=256) s[i]=par[O_BENC+i];
        __syncthreads();

        int n = b * 256 + tid;
        if (n < NN) {
            f4* sWc4 = (f4*)sm.emb.wc;  f4* sbc4 = (f4*)sm.emb.bc;
            f4* sTc4 = (f4*)sm.emb.tc;  f4* sTp4 = (f4*)sm.emb.tp;  f4* sTv4 = (f4*)sm.emb.tv;
            f4* sWcat4 = (f4*)sm.emb.wcat; f4* sbcat4 = (f4*)sm.emb.bcat;
            f4* sWe4 = (f4*)sm.emb.we;  f4* sbe4 = (f4*)sm.emb.be;

            float x0,x1,x2,x3,x4,x5;
            if (*a.flagw) {
                const float* xr = (const float*)a.xc + (size_t)n * 6;
                x0=xr[0]; x1=xr[1]; x2=xr[2]; x3=xr[3]; x4=xr[4]; x5=xr[5];
            } else {
                const unsigned* xr = (const unsigned*)a.xc + (size_t)n * 3;
                unsigned w0=xr[0], w1=xr[1], w2=xr[2];
                x0=__uint_as_float(w0<<16); x1=__uint_as_float(w0 & 0xFFFF0000u);
                x2=__uint_as_float(w1<<16); x3=__uint_as_float(w1 & 0xFFFF0000u);
                x4=__uint_as_float(w2<<16); x5=__uint_as_float(w2 & 0xFFFF0000u);
            }

            f4 ec[4];
            #pragma unroll
            for (int g = 0; g < 4; g++) {
                f4 acc = sbc4[g];
                acc += x0 * sWc4[0*4+g]; acc += x1 * sWc4[1*4+g]; acc += x2 * sWc4[2*4+g];
                acc += x3 * sWc4[3*4+g]; acc += x4 * sWc4[4*4+g]; acc += x5 * sWc4[5*4+g];
                ec[g] = elu4(acc);
            }

            int c0 = a.xcat[n*3+0], c1 = a.xcat[n*3+1], c2 = a.xcat[n*3+2];
            int a0 = c0 < 0 ? -c0 : c0;
            int pi = (a0==1)?0:(a0==2)?1:(a0==11)?2:(a0==13)?3:(a0==22)?4:(a0==130)?5:6;
            int ci = c1 + 1;

            f4 t0a = sTc4[ci*2],  t0b = sTc4[ci*2+1];
            f4 t1a = sTp4[pi*2],  t1b = sTp4[pi*2+1];
            f4 t2a = sTv4[c2*2],  t2b = sTv4[c2*2+1];

            f4 ecat[4];
            #pragma unroll
            for (int g = 0; g < 4; g++) {
                f4 acc = sbcat4[g];
                #pragma unroll
                for (int k = 0; k < 4; k++) acc += t0a[k] * sWcat4[(k     )*4+g];
                #pragma unroll
                for (int k = 0; k < 4; k++) acc += t0b[k] * sWcat4[(4 + k )*4+g];
                #pragma unroll
                for (int k = 0; k < 4; k++) acc += t1a[k] * sWcat4[(8 + k )*4+g];
                #pragma unroll
                for (int k = 0; k < 4; k++) acc += t1b[k] * sWcat4[(12 + k)*4+g];
                #pragma unroll
                for (int k = 0; k < 4; k++) acc += t2a[k] * sWcat4[(16 + k)*4+g];
                #pragma unroll
                for (int k = 0; k < 4; k++) acc += t2b[k] * sWcat4[(20 + k)*4+g];
                ecat[g] = elu4(acc);
            }

            f4* o = (f4*)(a.emb + (size_t)n * 32);
            #pragma unroll
            for (int cg2 = 0; cg2 < 8; cg2++) {
                f4 acc = sbe4[cg2];
                #pragma unroll
                for (int kg = 0; kg < 4; kg++) {
                    #pragma unroll
                    for (int k = 0; k < 4; k++)
                        acc += ecat[kg][k] * sWe4[(kg*4+k)*8 + cg2];
                }
                #pragma unroll
                for (int kg = 0; kg < 4; kg++) {
                    #pragma unroll
                    for (int k = 0; k < 4; k++)
                        acc += ec[kg][k] * sWe4[(16 + kg*4+k)*8 + cg2];
                }
                o[cg2] = elu4(acc);
            }
        }
    } else if (b < NB_SCAN + NCB) {
        for (int i = tid; i < NBUCK; i += 256) sm.cnt782[i] = 0;
        __syncthreads();
        int c = b - NB_SCAN;
        const int4v* dst4 = (const int4v*)(a.eidx + EE);
        int i0 = c * (NE4 / NCB);          // 3125 int4 per chunk
        int i1 = i0 + (NE4 / NCB);
        for (int i = i0 + tid; i < i1; i += 256) {
            int4v d = __builtin_nontemporal_load(&dst4[i]);
            atomicAdd(&sm.cnt782[d.x >> 7], 1);
            atomicAdd(&sm.cnt782[d.y >> 7], 1);
            atomicAdd(&sm.cnt782[d.z >> 7], 1);
            atomicAdd(&sm.cnt782[d.w >> 7], 1);
        }
        __syncthreads();
        for (int i = tid; i < NBUCK; i += 256) {
            int c2 = sm.cnt782[i];
            if (c2) atomicAdd(&a.curs[i * CPAD], c2);
        }
    }
    gg.sync();

    // ================= P2: scan782 (block 0) | bn1 stats over emb (blocks 1..G-1) =================
    if (b == 0) {
        int t4 = tid * 4;
        int v0=0,v1=0,v2=0,v3=0;
        if (t4   < NBUCK) v0 = a.curs[(t4  )*CPAD];
        if (t4+1 < NBUCK) v1 = a.curs[(t4+1)*CPAD];
        if (t4+2 < NBUCK) v2 = a.curs[(t4+2)*CPAD];
        if (t4+3 < NBUCK) v3 = a.curs[(t4+3)*CPAD];
        sm.scan.t[tid] = v0+v1+v2+v3;
        __syncthreads();
        for (int off = 1; off < 256; off <<= 1) {
            int x = (tid >= off) ? sm.scan.t[tid - off] : 0;
            __syncthreads();
            sm.scan.t[tid] += x;
            __syncthreads();
        }
        int run = tid ? sm.scan.t[tid-1] : 0;
        if (t4   < NBUCK) { a.base[t4  ] = run; a.curs[(t4  )*CPAD] = run; run += v0; }
        if (t4+1 < NBUCK) { a.base[t4+1] = run; a.curs[(t4+1)*CPAD] = run; run += v1; }
        if (t4+2 < NBUCK) { a.base[t4+2] = run; a.curs[(t4+2)*CPAD] = run; run += v2; }
        if (t4+3 < NBUCK) { a.base[t4+3] = run; a.curs[(t4+3)*CPAD] = run; run += v3; }
        if (tid == 255) a.base[NBUCK] = sm.scan.t[255];
        if (tid == 0)   a.rowp[NN] = EE;
    } else {
        if (tid < 64) sm.st.ls[tid] = 0.0f;
        __syncthreads();
        int idx = (b - 1) * 256 + tid;
        int stride = (G - 1) * 256;
        int c = idx & 31;
        float sum = 0.0f, q = 0.0f;
        for (int i = idx; i < NN * 32; i += stride) {
            float v = a.emb[i];
            sum += v; q += v * v;
        }
        sum += __shfl_xor(sum, 32);
        q   += __shfl_xor(q, 32);
        if ((tid & 63) < 32) {
            atomicAdd(&sm.st.ls[c], sum);
            atomicAdd(&sm.st.ls[32 + c], q);
        }
        __syncthreads();
        if (tid < 64) atomicAdd(&a.stats[tid], sm.st.ls[tid]);
    }
    gg.sync();

    // ================= P3: partition (0..390) | P,Q build (391..G-1) =================
    if (b < NPART) {
        for (int i = tid; i < NBUCK; i += 256) sm.part.cnt[i] = 0;
        __syncthreads();
        const int4v* src4 = (const int4v*)a.eidx;
        const int4v* dst4 = (const int4v*)(a.eidx + EE);
        int i0 = b << 10;
        int i1 = i0 + 1024; if (i1 > NE4) i1 = NE4;
        for (int i = i0 + tid; i < i1; i += 256) {
            int4v d = dst4[i];
            atomicAdd(&sm.part.cnt[d.x >> 7], 1);
            atomicAdd(&sm.part.cnt[d.y >> 7], 1);
            atomicAdd(&sm.part.cnt[d.z >> 7], 1);
            atomicAdd(&sm.part.cnt[d.w >> 7], 1);
        }
        __syncthreads();
        for (int i = tid; i < NBUCK; i += 256) {
            int c = sm.part.cnt[i];
            sm.part.start[i] = c ? atomicAdd(&a.curs[i * CPAD], c) : 0;
        }
        __syncthreads();
        for (int i = tid; i < NBUCK; i += 256) sm.part.cnt[i] = 0;
        __syncthreads();
        for (int i = i0 + tid; i < i1; i += 256) {
            int4v s = src4[i];
            int4v d = dst4[i];
            int bk, r;
            bk = d.x >> 7; r = atomicAdd(&sm.part.cnt[bk], 1); a.pe[sm.part.start[bk] + r] = (s.x << 7) | (d.x & 127);
            bk = d.y >> 7; r = atomicAdd(&sm.part.cnt[bk], 1); a.pe[sm.part.start[bk] + r] = (s.y << 7) | (d.y & 127);
            bk = d.z >> 7; r = atomicAdd(&sm.part.cnt[bk], 1); a.pe[sm.part.start[bk] + r] = (s.z << 7) | (d.z & 127);
            bk = d.w >> 7; r = atomicAdd(&sm.part.cnt[bk], 1); a.pe[sm.part.start[bk] + r] = (s.w << 7) | (d.w & 127);
        }
    } else {
        const float* par = a.par;
        if (tid < 32) {
            float mu  = a.stats[tid] * (1.0f / NN);
            float var = a.stats[32 + tid] * (1.0f / NN) - mu * mu;
            float sc  = par[O_GALL + tid] * rsqrtf(var + 1e-5f);
            sm.pq.ssc[tid] = sc;
            sm.pq.ssh[tid] = par[O_BEALL + tid] - mu * sc;
        }
        __syncthreads();
        for (int e = tid; e < 1024; e += 256) {
            int k = e >> 5;
            float w1 = par[O_WMSG + e];
            float w2 = par[O_WMSG + 1024 + e];
            sm.pq.wp[e] = sm.pq.ssc[k] * (w1 - w2);
            sm.pq.wq[e] = sm.pq.ssc[k] * w2;
        }
        if (tid < 32) {
            float aP = par[O_BMSG + tid], aQ = 0.0f;
            for (int k = 0; k < 32; k++) {
                float w1 = par[O_WMSG + k*32 + tid];
                float w2 = par[O_WMSG + (k+32)*32 + tid];
                aP += sm.pq.ssh[k] * (w1 - w2);
                aQ += sm.pq.ssh[k] * w2;
            }
            sm.pq.bp[tid] = aP;
            sm.pq.bq[tid] = aQ;
        }
        __syncthreads();

        int n = (b - NPART) * 256 + tid;
        if (n < NN) {
            f4* sWP4 = (f4*)sm.pq.wp; f4* sWQ4 = (f4*)sm.pq.wq;
            f4* sbP4 = (f4*)sm.pq.bp; f4* sbQ4 = (f4*)sm.pq.bq;
            const f4* er = (const f4*)(a.emb + (size_t)n * 32);
            f4 e[8];
            #pragma unroll
            for (int g = 0; g < 8; g++) e[g] = er[g];
            f4* pr = (f4*)(a.P + (size_t)n * 32);
            f4* qr = (f4*)(a.Q + (size_t)n * 32);
            #pragma unroll
            for (int cg2 = 0; cg2 < 8; cg2++) {
                f4 aP = sbP4[cg2];
                f4 aQ = sbQ4[cg2];
                #pragma unroll
                for (int kg = 0; kg < 8; kg++) {
                    #pragma unroll
                    for (int k = 0; k < 4; k++) {
                        float ek = e[kg][k];
                        aP += ek * sWP4[(kg*4+k)*8 + cg2];
                        aQ += ek * sWQ4[(kg*4+k)*8 + cg2];
                    }
                }
                pr[cg2] = aP;
                qr[cg2] = aQ;
            }
        }
    }
    gg.sync();

    // ================= P4: per-bucket CSR (blocks 0..781) =================
    if (b < NBUCK) {
        int beg = a.base[b], end = a.base[b + 1];
        int m = end - beg;
        if (tid < 128) sm.csr.cnt[tid] = 0;
        __syncthreads();
        for (int i = tid; i < m; i += 256) {
            int p = a.pe[beg + i];
            if (i < BCAP) sm.csr.stage[i] = p;
            atomicAdd(&sm.csr.cnt[p & 127], 1);
        }
        __syncthreads();
        if (tid < 128) sm.csr.sc[tid] = sm.csr.cnt[tid];
        __syncthreads();
        for (int off = 1; off < 128; off <<= 1) {
            int x = (tid >= off && tid < 128) ? sm.csr.sc[tid - off] : 0;
            __syncthreads();
            if (tid < 128) sm.csr.sc[tid] += x;
            __syncthreads();
        }
        if (tid < 128) {
            int e0 = sm.csr.sc[tid] - sm.csr.cnt[tid];
            sm.csr.ex[tid] = e0;
            int node = b * 128 + tid;
            if (node < NN) a.rowp[node] = beg + e0;
            sm.csr.cnt[tid] = 0;
        }
        __syncthreads();
        for (int i = tid; i < m; i += 256) {
            int p = (i < BCAP) ? sm.csr.stage[i] : a.pe[beg + i];
            int dl = p & 127;
            int r = atomicAdd(&sm.csr.cnt[dl], 1);
            a.srcl[beg + sm.csr.ex[dl] + r] = p >> 7;
        }
    }
    gg.sync();

    // ================= P5: gather-max (all blocks, 2 nodes/wave) + bn2 stats fused =================
    {
        if (tid < 64) sm.st.ls[tid] = 0.0f;
        __syncthreads();
        int lane = tid & 63;
        int wave = tid >> 6;
        int w = b * 4 + wave;
        int half  = lane >> 5;
        int hl    = lane & 31;
        int slice = hl >> 3;               // 0..3 edge slice
        int cg    = hl & 7;                // channel group
        const f4* Q4 = (const f4*)a.Q;
        for (int n0 = w * 2; n0 < NN; n0 += G * 8) {
            int n2 = n0 + half;
            int beg = a.rowp[n2], end = a.rowp[n2 + 1];
            f4 pv = (f4){0.f, 0.f, 0.f, 0.f};
            if (hl < 8 && end > beg) pv = ((const f4*)a.P)[(size_t)n2 * 8 + hl];
            f4 m = {-INFINITY, -INFINITY, -INFINITY, -INFINITY};
            for (int e = beg + slice; e < end; e += 16) {
                int e1 = min(e + 4,  end - 1);
                int e2 = min(e + 8,  end - 1);
                int e3 = min(e + 12, end - 1);
                int s0 = __builtin_nontemporal_load(&a.srcl[e]);
                int s1 = __builtin_nontemporal_load(&a.srcl[e1]);
                int s2 = __builtin_nontemporal_load(&a.srcl[e2]);
                int s3 = __builtin_nontemporal_load(&a.srcl[e3]);
                f4 q0 = Q4[(size_t)s0 * 8 + cg];
                f4 q1 = Q4[(size_t)s1 * 8 + cg];
                f4 q2 = Q4[(size_t)s2 * 8 + cg];
                f4 q3 = Q4[(size_t)s3 * 8 + cg];
                q0 = f4max(q0, q1);
                q2 = f4max(q2, q3);
                m = f4max(m, f4max(q0, q2));
            }
            #pragma unroll
            for (int off = 8; off < 32; off <<= 1) {
                m.x = fmaxf(m.x, __shfl_xor(m.x, off));
                m.y = fmaxf(m.y, __shfl_xor(m.y, off));
                m.z = fmaxf(m.z, __shfl_xor(m.z, off));
                m.w = fmaxf(m.w, __shfl_xor(m.w, off));
            }
            if (hl < 8) {
                f4 o;
                if (end > beg) o = m + pv;
                else           o = (f4){0.f, 0.f, 0.f, 0.f};
                ((f4*)a.agg)[(size_t)n2 * 8 + hl] = o;
                atomicAdd(&sm.st.ls[hl*4+0], o.x);
                atomicAdd(&sm.st.ls[hl*4+1], o.y);
                atomicAdd(&sm.st.ls[hl*4+2], o.z);
                atomicAdd(&sm.st.ls[hl*4+3], o.w);
                atomicAdd(&sm.st.ls[32+hl*4+0], o.x*o.x);
                atomicAdd(&sm.st.ls[32+hl*4+1], o.y*o.y);
                atomicAdd(&sm.st.ls[32+hl*4+2], o.z*o.z);
                atomicAdd(&sm.st.ls[32+hl*4+3], o.w*o.w);
            }
        }
        __syncthreads();
        if (tid < 64) atomicAdd(&a.stats[64 + tid], sm.st.ls[tid]);
    }
    gg.sync();

    // ================= P6: output MLP (blocks 0..390) =================
    if (b < NB_SCAN) {
        const float* par = a.par;
        for (int i = tid; i < 512; i += 256) sm.outp.w1[i] = par[O_WOUT1 + i];
        if (tid < 16) {
            sm.outp.b1[tid] = par[O_BOUT1 + tid];
            sm.outp.w2[tid] = par[O_WOUT2 + tid];
        }
        if (tid < 32) {
            float mu  = a.stats[tid] * (1.0f / NN);
            float var = a.stats[32 + tid] * (1.0f / NN) - mu * mu;
            float sc  = par[O_GALL + tid] * rsqrtf(var + 1e-5f);
            sm.outp.sc1[tid] = sc;
            sm.outp.sh1[tid] = par[O_BEALL + tid] - mu * sc;
            float mu2  = a.stats[64 + tid] * (1.0f / NN);
            float var2 = a.stats[96 + tid] * (1.0f / NN) - mu2 * mu2;
            float s2   = par[O_GCONV + tid] * rsqrtf(var2 + 1e-5f);
            sm.outp.sc2[tid] = s2;
            sm.outp.sh2[tid] = par[O_BECONV + tid] - mu2 * s2;
        }
        if (tid == 0) sm.outp.b2s = par[O_BOUT2];
        __syncthreads();

        int n = b * 256 + tid;
        if (n < NN) {
            f4* sW14 = (f4*)sm.outp.w1; f4* sb14 = (f4*)sm.outp.b1; f4* sW24 = (f4*)sm.outp.w2;
            f4* sc14 = (f4*)sm.outp.sc1; f4* sh14 = (f4*)sm.outp.sh1;
            f4* sc24 = (f4*)sm.outp.sc2; f4* sh24 = (f4*)sm.outp.sh2;
            const f4* er = (const f4*)(a.emb + (size_t)n * 32);
            const f4* ar = (const f4*)(a.agg + (size_t)n * 32);
            f4 h[8];
            #pragma unroll
            for (int g = 0; g < 8; g++) {
                f4 ev = er[g];
                f4 av = ar[g];
                h[g] = ev * sc14[g] + sh14[g] + av * sc24[g] + sh24[g];
            }
            f4 o1[4];
            #pragma unroll
            for (int g = 0; g < 4; g++) {
                f4 acc = sb14[g];
                #pragma unroll
                for (int kg = 0; kg < 8; kg++) {
                    #pragma unroll
                    for (int k = 0; k < 4; k++)
                        acc += h[kg][k] * sW14[(kg*4+k)*4 + g];
                }
                o1[g] = elu4(acc);
            }
            float acc = sm.outp.b2s;
            #pragma unroll
            for (int g = 0; g < 4; g++) {
                f4 p = o1[g] * sW24[g];
                acc += p.x + p.y + p.z + p.w;
            }
            if (*a.flagw) ((float*)a.out)[n] = acc;
            else          ((bf16_t*)a.out)[n] = __float2bfloat16(acc);
        }
    }
}

// ======================= FALLBACK KERNELS (round-2 proven path) =======================

struct InitArgs {
    const void* p[19];
    const unsigned short* wdet;
    int*        flagw;
    float*      par;
    int*        curs;
    float*      stats;
};

__global__ __launch_bounds__(256) void k_init(InitArgs a)
{
    const int offs[20] = {O_WCONT,O_BCONT,O_TCHRG,O_TPDG,O_TPV,O_WCAT,O_BCAT,O_WENC,
                          O_BENC,O_GALL,O_BEALL,O_WMSG,O_BMSG,O_GCONV,O_BECONV,
                          O_WOUT1,O_BOUT1,O_WOUT2,O_BOUT2,NPAR};
    __shared__ int sflag;
    int b = blockIdx.x, tid = threadIdx.x;
    int g = b * 256 + tid;
    if (g < NBUCK * CPAD) a.curs[g] = 0;
    if (g < 128) a.stats[g] = 0.0f;
    if (b == 0) {
        if (tid == 0) sflag = 0;
        __syncthreads();
        int bad = 0;
        for (int i = tid; i < 1024; i += 256) {
            unsigned e = (a.wdet[i] >> 7) & 0xFFu;
            if (e >= 137u) bad = 1;
        }
        if (bad) atomicOr(&sflag, 1);
        __syncthreads();
        int f32 = sflag;
        if (tid == 0) *a.flagw = f32;
        for (int i = tid; i < NPAR; i += 256) {
            int t = 0;
            while (offs[t + 1] <= i) t++;
            int l = i - offs[t];
            const void* s = a.p[t];
            a.par[i] = f32 ? ((const float*)s)[l] : bf(((const unsigned short*)s)[l]);
        }
    }
}

__global__ __launch_bounds__(256, 1) void k_fusedA(
    const int* __restrict__ eidx, int* __restrict__ curs,
    const void* __restrict__ xc, const int* __restrict__ x_cat,
    const float* __restrict__ par, const int* __restrict__ flag,
    float* __restrict__ emb)
{
    __shared__ f4 sWc4[24];
    __shared__ f4 sbc4[4];
    __shared__ f4 sTc4[6], sTp4[14], sTv4[16];
    __shared__ f4 sWcat4[96];
    __shared__ f4 sbcat4[4];
    __shared__ f4 sWe4[256];
    __shared__ f4 sbe4[8];
    int tid = threadIdx.x;
    int b = blockIdx.x;

    if (b < NCB) {
        __shared__ int cnt[NBUCK];
        for (int i = tid; i < NBUCK; i += 256) cnt[i] = 0;
        __syncthreads();
        const int4v* dst4 = (const int4v*)(eidx + EE);
        int i0 = b * (NE4 / NCB);
        int i1 = i0 + (NE4 / NCB);
        for (int i = i0 + tid; i < i1; i += 256) {
            int4v d = __builtin_nontemporal_load(&dst4[i]);
            atomicAdd(&cnt[d.x >> 7], 1);
            atomicAdd(&cnt[d.y >> 7], 1);
            atomicAdd(&cnt[d.z >> 7], 1);
            atomicAdd(&cnt[d.w >> 7], 1);
        }
        __syncthreads();
        for (int i = tid; i < NBUCK; i += 256) {
            int c = cnt[i];
            if (c) atomicAdd(&curs[i * CPAD], c);
        }
        return;
    }

    {
        float* s;
        s=(float*)sWc4;   for(int i=tid;i<96;  i+=256) s[i]=par[O_WCONT+i];
        s=(float*)sbc4;   for(int i=tid;i<16;  i+=256) s[i]=par[O_BCONT+i];
        s=(float*)sTc4;   for(int i=tid;i<24;  i+=256) s[i]=par[O_TCHRG+i];
        s=(float*)sTp4;   for(int i=tid;i<56;  i+=256) s[i]=par[O_TPDG+i];
        s=(float*)sTv4;   for(int i=tid;i<64;  i+=256) s[i]=par[O_TPV+i];
        s=(float*)sWcat4; for(int i=tid;i<384; i+=256) s[i]=par[O_WCAT+i];
        s=(float*)sbcat4; for(int i=tid;i<16;  i+=256) s[i]=par[O_BCAT+i];
        s=(float*)sWe4;   for(int i=tid;i<1024;i+=256) s[i]=par[O_WENC+i];
        s=(float*)sbe4;   for(int i=tid;i<32;  i+=256) s[i]=par[O_BENC+i];
    }
    __syncthreads();

    int n = (b - NCB) * 256 + tid;
    if (n >= NN) return;

    float x0,x1,x2,x3,x4,x5;
    if (*flag) {
        const float* xr = (const float*)xc + (size_t)n * 6;
        x0=xr[0]; x1=xr[1]; x2=xr[2]; x3=xr[3]; x4=xr[4]; x5=xr[5];
    } else {
        const unsigned* xr = (const unsigned*)xc + (size_t)n * 3;
        unsigned w0=xr[0], w1=xr[1], w2=xr[2];
        x0=__uint_as_float(w0<<16); x1=__uint_as_float(w0 & 0xFFFF0000u);
        x2=__uint_as_float(w1<<16); x3=__uint_as_float(w1 & 0xFFFF0000u);
        x4=__uint_as_float(w2<<16); x5=__uint_as_float(w2 & 0xFFFF0000u);
    }

    f4 ec[4];
    #pragma unroll
    for (int g = 0; g < 4; g++) {
        f4 a = sbc4[g];
        a += x0 * sWc4[0*4+g]; a += x1 * sWc4[1*4+g]; a += x2 * sWc4[2*4+g];
        a += x3 * sWc4[3*4+g]; a += x4 * sWc4[4*4+g]; a += x5 * sWc4[5*4+g];
        ec[g] = elu4(a);
    }

    int c0 = x_cat[n*3+0], c1 = x_cat[n*3+1], c2 = x_cat[n*3+2];
    int a0 = c0 < 0 ? -c0 : c0;
    int pi = (a0==1)?0:(a0==2)?1:(a0==11)?2:(a0==13)?3:(a0==22)?4:(a0==130)?5:6;
    int ci = c1 + 1;

    f4 t0a = sTc4[ci*2],  t0b = sTc4[ci*2+1];
    f4 t1a = sTp4[pi*2],  t1b = sTp4[pi*2+1];
    f4 t2a = sTv4[c2*2],  t2b = sTv4[c2*2+1];

    f4 ecat[4];
    #pragma unroll
    for (int g = 0; g < 4; g++) {
        f4 a = sbcat4[g];
        #pragma unroll
        for (int k = 0; k < 4; k++) a += t0a[k] * sWcat4[(k     )*4+g];
        #pragma unroll
        for (int k = 0; k < 4; k++) a += t0b[k] * sWcat4[(4 + k )*4+g];
        #pragma unroll
        for (int k = 0; k < 4; k++) a += t1a[k] * sWcat4[(8 + k )*4+g];
        #pragma unroll
        for (int k = 0; k < 4; k++) a += t1b[k] * sWcat4[(12 + k)*4+g];
        #pragma unroll
        for (int k = 0; k < 4; k++) a += t2a[k] * sWcat4[(16 + k)*4+g];
        #pragma unroll
        for (int k = 0; k < 4; k++) a += t2b[k] * sWcat4[(20 + k)*4+g];
        ecat[g] = elu4(a);
    }

    f4* o = (f4*)(emb + (size_t)n * 32);
    #pragma unroll
    for (int cg = 0; cg < 8; cg++) {
        f4 a = sbe4[cg];
        #pragma unroll
        for (int kg = 0; kg < 4; kg++) {
            #pragma unroll
            for (int k = 0; k < 4; k++)
                a += ecat[kg][k] * sWe4[(kg*4+k)*8 + cg];
        }
        #pragma unroll
        for (int kg = 0; kg < 4; kg++) {
            #pragma unroll
            for (int k = 0; k < 4; k++)
                a += ec[kg][k] * sWe4[(16 + kg*4+k)*8 + cg];
        }
        o[cg] = elu4(a);
    }
}

__global__ __launch_bounds__(1024) void k_scan782(int* __restrict__ curs,
                                                  int* __restrict__ base,
                                                  int* __restrict__ rowp)
{
    __shared__ int s[1024];
    int tid = threadIdx.x;
    int v = (tid < NBUCK) ? curs[tid * CPAD] : 0;
    s[tid] = v;
    __syncthreads();
    for (int off = 1; off < 1024; off <<= 1) {
        int x = (tid >= off) ? s[tid - off] : 0;
        __syncthreads();
        s[tid] += x;
        __syncthreads();
    }
    if (tid < NBUCK) {
        int bexc = s[tid] - v;
        base[tid] = bexc;
        curs[tid * CPAD] = bexc;
    }
    if (tid == NBUCK - 1) base[NBUCK] = s[tid];
    if (tid == 0) rowp[NN] = EE;
}

__global__ __launch_bounds__(256, 1) void k_partition(
    const int* __restrict__ eidx, int* __restrict__ curs, int* __restrict__ pe)
{
    __shared__ int cnt[NBUCK];
    __shared__ int start[NBUCK];
    int tid = threadIdx.x;
    int b = blockIdx.x;
    for (int i = tid; i < NBUCK; i += 256) cnt[i] = 0;
    __syncthreads();

    const int4v* src4 = (const int4v*)eidx;
    const int4v* dst4 = (const int4v*)(eidx + EE);
    int i0 = b << 10;
    int i1 = i0 + 1024; if (i1 > NE4) i1 = NE4;

    for (int i = i0 + tid; i < i1; i += 256) {
        int4v d = dst4[i];
        atomicAdd(&cnt[d.x >> 7], 1);
        atomicAdd(&cnt[d.y >> 7], 1);
        atomicAdd(&cnt[d.z >> 7], 1);
        atomicAdd(&cnt[d.w >> 7], 1);
    }
    __syncthreads();
    for (int i = tid; i < NBUCK; i += 256) {
        int c = cnt[i];
        start[i] = c ? atomicAdd(&curs[i * CPAD], c) : 0;
    }
    __syncthreads();
    for (int i = tid; i < NBUCK; i += 256) cnt[i] = 0;
    __syncthreads();
    for (int i = i0 + tid; i < i1; i += 256) {
        int4v s = src4[i];
        int4v d = dst4[i];
        int bk, r;
        bk = d.x >> 7; r = atomicAdd(&cnt[bk], 1); pe[start[bk] + r] = (s.x << 7) | (d.x & 127);
        bk = d.y >> 7; r = atomicAdd(&cnt[bk], 1); pe[start[bk] + r] = (s.y << 7) | (d.y & 127);
        bk = d.z >> 7; r = atomicAdd(&cnt[bk], 1); pe[start[bk] + r] = (s.z << 7) | (d.z & 127);
        bk = d.w >> 7; r = atomicAdd(&cnt[bk], 1); pe[start[bk] + r] = (s.w << 7) | (d.w & 127);
    }
}

__global__ __launch_bounds__(256) void k_fusedB(
    const int* __restrict__ cbase, const int* __restrict__ pe,
    int* __restrict__ rowp, int* __restrict__ srcl,
    const float* __restrict__ emb, float* __restrict__ stats)
{
    __shared__ int stage[BCAP];
    __shared__ int cnt[128], sc[128], ex[128];
    __shared__ float ls[64];
    int tid = threadIdx.x;
    int b = blockIdx.x;
    if (b < NBUCK) {
        int beg = cbase[b], end = cbase[b + 1];
        int m = end - beg;
        if (tid < 128) cnt[tid] = 0;
        __syncthreads();
        for (int i = tid; i < m; i += 256) {
            int p = pe[beg + i];
            if (i < BCAP) stage[i] = p;
            atomicAdd(&cnt[p & 127], 1);
        }
        __syncthreads();
        if (tid < 128) sc[tid] = cnt[tid];
        __syncthreads();
        for (int off = 1; off < 128; off <<= 1) {
            int x = (tid >= off && tid < 128) ? sc[tid - off] : 0;
            __syncthreads();
            if (tid < 128) sc[tid] += x;
            __syncthreads();
        }
        if (tid < 128) {
            int e0 = sc[tid] - cnt[tid];
            ex[tid] = e0;
            int node = b * 128 + tid;
            if (node < NN) rowp[node] = beg + e0;
            cnt[tid] = 0;
        }
        __syncthreads();
        for (int i = tid; i < m; i += 256) {
            int p = (i < BCAP) ? stage[i] : pe[beg + i];
            int dl = p & 127;
            int r = atomicAdd(&cnt[dl], 1);
            srcl[beg + ex[dl] + r] = p >> 7;
        }
        return;
    }
    if (tid < 64) ls[tid] = 0.0f;
    __syncthreads();
    int sb = b - NBUCK;
    int idx = sb * 256 + tid;
    int stride = 512 * 256;
    int c = idx & 31;
    float sum = 0.0f, q = 0.0f;
    for (int i = idx; i < NN * 32; i += stride) {
        float v = emb[i];
        sum += v; q += v * v;
    }
    sum += __shfl_xor(sum, 32);
    q   += __shfl_xor(q, 32);
    if ((tid & 63) < 32) {
        atomicAdd(&ls[c], sum);
        atomicAdd(&ls[32 + c], q);
    }
    __syncthreads();
    if (tid < 64) atomicAdd(&stats[tid], ls[tid]);
}

__global__ __launch_bounds__(256, 1) void k_fusedC(
    const float* __restrict__ par, const float* __restrict__ stats,
    const float* __restrict__ emb, float* __restrict__ P, float* __restrict__ Q)
{
    __shared__ f4 sWP4[256], sWQ4[256];
    __shared__ f4 sbP4[8], sbQ4[8];
    __shared__ float ssc[32], ssh[32];
    int tid = threadIdx.x;
    int b = blockIdx.x;
    if (tid < 32) {
        float mu  = stats[tid] * (1.0f / NN);
        float var = stats[32 + tid] * (1.0f / NN) - mu * mu;
        float s   = par[O_GALL + tid] * rsqrtf(var + 1e-5f);
        ssc[tid] = s;
        ssh[tid] = par[O_BEALL + tid] - mu * s;
    }
    __syncthreads();
    {
        float* wp = (float*)sWP4;
        float* wq = (float*)sWQ4;
        for (int e = tid; e < 1024; e += 256) {
            int k = e >> 5;
            float w1 = par[O_WMSG + e];
            float w2 = par[O_WMSG + 1024 + e];
            wp[e] = ssc[k] * (w1 - w2);
            wq[e] = ssc[k] * w2;
        }
    }
    if (tid < 32) {
        float aP = par[O_BMSG + tid], aQ = 0.0f;
        for (int k = 0; k < 32; k++) {
            float w1 = par[O_WMSG + k*32 + tid];
            float w2 = par[O_WMSG + (k+32)*32 + tid];
            aP += ssh[k] * (w1 - w2);
            aQ += ssh[k] * w2;
        }
        ((float*)sbP4)[tid] = aP;
        ((float*)sbQ4)[tid] = aQ;
    }
    __syncthreads();

    int n = b * 256 + tid;
    if (n >= NN) return;

    const f4* er = (const f4*)(emb + (size_t)n * 32);
    f4 e[8];
    #pragma unroll
    for (int g = 0; g < 8; g++) e[g] = er[g];

    f4* pr = (f4*)(P + (size_t)n * 32);
    f4* qr = (f4*)(Q + (size_t)n * 32);
    #pragma unroll
    for (int cg = 0; cg < 8; cg++) {
        f4 aP = sbP4[cg];
        f4 aQ = sbQ4[cg];
        #pragma unroll
        for (int kg = 0; kg < 8; kg++) {
            #pragma unroll
            for (int k = 0; k < 4; k++) {
                float ek = e[kg][k];
                aP += ek * sWP4[(kg*4+k)*8 + cg];
                aQ += ek * sWQ4[(kg*4+k)*8 + cg];
            }
        }
        pr[cg] = aP;
        qr[cg] = aQ;
    }
}

__global__ __launch_bounds__(256) void k_gather(
    const int* __restrict__ rowp, const int* __restrict__ srcl,
    const float* __restrict__ Q, const float* __restrict__ P,
    float* __restrict__ agg)
{
    int tid = threadIdx.x;
    int lane = tid & 63;
    int wave = tid >> 6;
    int n = blockIdx.x * 4 + wave;
    int slice = lane >> 3;
    int cg    = lane & 7;
    int beg = rowp[n], end = rowp[n + 1];
    const f4* Q4 = (const f4*)Q;

    f4 pv = (f4){0.f, 0.f, 0.f, 0.f};
    if (lane < 8 && end > beg) pv = ((const f4*)P)[(size_t)n * 8 + lane];

    f4 m = {-INFINITY, -INFINITY, -INFINITY, -INFINITY};
    for (int e = beg + slice; e < end; e += 32) {
        int e1 = min(e + 8,  end - 1);
        int e2 = min(e + 16, end - 1);
        int e3 = min(e + 24, end - 1);
        int s0 = __builtin_nontemporal_load(&srcl[e]);
        int s1 = __builtin_nontemporal_load(&srcl[e1]);
        int s2 = __builtin_nontemporal_load(&srcl[e2]);
        int s3 = __builtin_nontemporal_load(&srcl[e3]);
        f4 q0 = Q4[(size_t)s0 * 8 + cg];
        f4 q1 = Q4[(size_t)s1 * 8 + cg];
        f4 q2 = Q4[(size_t)s2 * 8 + cg];
        f4 q3 = Q4[(size_t)s3 * 8 + cg];
        q0 = f4max(q0, q1);
        q2 = f4max(q2, q3);
        m = f4max(m, f4max(q0, q2));
    }
    #pragma unroll
    for (int off = 8; off < 64; off <<= 1) {
        m.x = fmaxf(m.x, __shfl_xor(m.x, off));
        m.y = fmaxf(m.y, __shfl_xor(m.y, off));
        m.z = fmaxf(m.z, __shfl_xor(m.z, off));
        m.w = fmaxf(m.w, __shfl_xor(m.w, off));
    }
    if (lane < 8) {
        f4 o;
        if (end > beg) o = m + pv;
        else           o = (f4){0.f, 0.f, 0.f, 0.f};
        ((f4*)agg)[(size_t)n * 8 + lane] = o;
    }
}

__global__ __launch_bounds__(256) void k_stats(const float* __restrict__ xin,
                                               float* __restrict__ outsums, int count)
{
    __shared__ float ls[64];
    int tid = threadIdx.x;
    if (tid < 64) ls[tid] = 0.0f;
    __syncthreads();
    int idx = blockIdx.x * 256 + tid;
    int stride = gridDim.x * 256;
    int c = idx & 31;
    float s = 0.0f, q = 0.0f;
    for (int i = idx; i < count; i += stride) {
        float v = xin[i];
        s += v; q += v * v;
    }
    s += __shfl_xor(s, 32);
    q += __shfl_xor(q, 32);
    if ((tid & 63) < 32) {
        atomicAdd(&ls[c], s);
        atomicAdd(&ls[32 + c], q);
    }
    __syncthreads();
    if (tid < 64) atomicAdd(&outsums[tid], ls[tid]);
}

__global__ __launch_bounds__(256, 1) void k_out(
    const float* __restrict__ emb, const float* __restrict__ agg,
    const float* __restrict__ par, const float* __restrict__ stats,
    const int* __restrict__ flag, void* __restrict__ out)
{
    __shared__ f4 sW14[128];
    __shared__ f4 sb14[4], sW24[4];
    __shared__ f4 sc14[8], sh14[8], sc24[8], sh24[8];
    __shared__ float sb2s;
    int tid = threadIdx.x;
    {
        float* s = (float*)sW14;
        for (int i = tid; i < 512; i += 256) s[i] = par[O_WOUT1 + i];
    }
    if (tid < 16) {
        ((float*)sb14)[tid] = par[O_BOUT1 + tid];
        ((float*)sW24)[tid] = par[O_WOUT2 + tid];
    }
    if (tid < 32) {
        float mu  = stats[tid] * (1.0f / NN);
        float var = stats[32 + tid] * (1.0f / NN) - mu * mu;
        float s   = par[O_GALL + tid] * rsqrtf(var + 1e-5f);
        ((float*)sc14)[tid] = s;
        ((float*)sh14)[tid] = par[O_BEALL + tid] - mu * s;
        float mu2  = stats[64 + tid] * (1.0f / NN);
        float var2 = stats[96 + tid] * (1.0f / NN) - mu2 * mu2;
        float s2   = par[O_GCONV + tid] * rsqrtf(var2 + 1e-5f);
        ((float*)sc24)[tid] = s2;
        ((float*)sh24)[tid] = par[O_BECONV + tid] - mu2 * s2;
    }
    if (tid == 0) sb2s = par[O_BOUT2];
    __syncthreads();

    int n = blockIdx.x * 256 + tid;
    if (n >= NN) return;

    const f4* er = (const f4*)(emb + (size_t)n * 32);
    const f4* ar = (const f4*)(agg + (size_t)n * 32);
    f4 h[8];
    #pragma unroll
    for (int g = 0; g < 8; g++) {
        f4 ev = er[g];
        f4 av = ar[g];
        h[g] = ev * sc14[g] + sh14[g] + av * sc24[g] + sh24[g];
    }
    f4 o1[4];
    #pragma unroll
    for (int g = 0; g < 4; g++) {
        f4 acc = sb14[g];
        #pragma unroll
        for (int kg = 0; kg < 8; kg++) {
            #pragma unroll
            for (int k = 0; k < 4; k++)
                acc += h[kg][k] * sW14[(kg*4+k)*4 + g];
        }
        o1[g] = elu4(acc);
    }
    float acc = sb2s;
    #pragma unroll
    for (int g = 0; g < 4; g++) {
        f4 p = o1[g] * sW24[g];
        acc += p.x + p.y + p.z + p.w;
    }

    if (*flag) ((float*)out)[n] = acc;
    else       ((bf16_t*)out)[n] = __float2bfloat16(acc);
}

// ======================= launcher =======================

extern "C" void kernel_launch(void* const* d_in, const int* in_sizes, int n_in,
                              void* d_out, int out_size, void* d_ws, size_t ws_size,
                              hipStream_t stream)
{
    const void* x_cont = d_in[0];
    const int* x_cat = (const int*)d_in[1];
    const int* eidx  = (const int*)d_in[2];

    float* ws    = (float*)d_ws;
    float* par   = ws + PARB;
    float* emb   = ws + EMB;
    float* P     = ws + PBUF;
    float* Q     = ws + QBUF;
    float* agg   = ws + ABUF;
    int*   pe    = (int*)(ws + ABUF);
    float* stats = ws + SOFF;
    int*   flag  = (int*)(stats + 128);
    int*   curs  = (int*)(ws + CURS);
    int*   base  = (int*)(ws + BASEO);
    int*   rowp  = (int*)(ws + ROWP);
    int*   srcl  = (int*)(ws + SRCL);

    // ---- try cooperative mega-kernel ----
    static int coop_state = -1;   // -1 unknown, 0 no, >0 = grid size
    if (coop_state == -1) {
        int dev = 0;
        hipGetDevice(&dev);
        int coop = 0;
        hipDeviceGetAttribute(&coop, hipDeviceAttributeCooperativeLaunch, dev);
        int ncu = 0;
        hipDeviceGetAttribute(&ncu, hipDeviceAttributeMultiprocessorCount, dev);
        int nb = 0;
        hipOccupancyMaxActiveBlocksPerMultiprocessor(&nb, k_mega, 256, 0);
        int mg = ncu * nb;
        if (mg > 1024) mg = 1024;
        coop_state = (coop && mg >= 2 * NB_SCAN) ? mg : 0;
    }

    if (coop_state > 0) {
        MegaArgs ma;
        for (int t = 0; t < 19; t++) ma.p[t] = d_in[4 + t];
        ma.wdet = (const unsigned short*)d_in[11];
        ma.eidx = eidx; ma.xc = x_cont; ma.xcat = x_cat;
        ma.par = par; ma.flagw = flag; ma.curs = curs; ma.stats = stats;
        ma.base = base; ma.rowp = rowp; ma.srcl = srcl; ma.pe = pe;
        ma.emb = emb; ma.P = P; ma.Q = Q; ma.agg = agg; ma.out = d_out;
        void* kargs[] = { &ma };
        hipError_t rc = hipLaunchCooperativeKernel((const void*)k_mega, dim3(coop_state),
                                                   dim3(256), kargs, 0, stream);
        if (rc == hipSuccess) return;
        (void)hipGetLastError();
        coop_state = 0;   // never try again
    }

    // ---- fallback: proven round-2 sequence ----
    InitArgs ia;
    for (int t = 0; t < 19; t++) ia.p[t] = d_in[4 + t];
    ia.wdet = (const unsigned short*)d_in[11];
    ia.flagw = flag; ia.par = par; ia.curs = curs; ia.stats = stats;
    k_init<<<NB_SCAN, 256, 0, stream>>>(ia);

    k_fusedA<<<NCB + NB_SCAN, 256, 0, stream>>>(eidx, curs, x_cont, x_cat,
                                                par, flag, emb);
    k_scan782<<<1, 1024, 0, stream>>>(curs, base, rowp);
    k_partition<<<NPART, 256, 0, stream>>>(eidx, curs, pe);
    k_fusedB<<<NBUCK + 512, 256, 0, stream>>>(base, pe, rowp, srcl, emb, stats);
    k_fusedC<<<NB_SCAN, 256, 0, stream>>>(par, stats, emb, P, Q);
    k_gather<<<NN / 4, 256, 0, stream>>>(rowp, srcl, Q, P, agg);
    k_stats<<<512, 256, 0, stream>>>(agg, stats + 64, NN * 32);
    k_out<<<NB_SCAN, 256, 0, stream>>>(emb, agg, par, stats, flag, d_out);
}

// Round 4
// 286.006 us; speedup vs baseline: 1.3492x; 1.0203x over previous
//
#include <hip/hip_runtime.h>
#include <hip/hip_bf16.h>

#define NN 100000
#define EE 1600000
#define NB_SCAN 391   // ceil(NN/256)

// ---- bucketed CSR parameters ----
#define NBUCK 782     // dst>>7 -> 782 buckets of 128 nodes
#define CPAD  16      // cursor padding (64B) to kill line contention
#define NPART 391     // partition chunks (4096 edges each)
#define NE4   400000  // EE/4
#define CAP   4096    // fixed slots per bucket (mean 2046, sd ~45 -> 45 sigma)
#define CAPSH 12
#define BCAP  2560    // LDS staging capacity per bucket

typedef __hip_bfloat16 bf16_t;
typedef int int4v __attribute__((ext_vector_type(4)));
typedef float f4 __attribute__((ext_vector_type(4)));

// ---- workspace layout (float offsets); ws is 256 MiB ----
#define PARB  600000            // params fp32 (4465)
#define EMB   604480            // N*32 raw embeddings
#define PBUF  3804480           // N*32 P'
#define QBUF  7004480           // N*32 Q
#define ABUF  10204480          // N*32 agg
#define SOFF  13404480          // stats: [0:32) sum1 [32:64) sq1; [128] flag
#define PART2 (SOFF + 256)      // 64 replicas x 64 fp32 bn2 partials
#define CURS  (PART2 + 4096)    // NBUCK*CPAD ints
#define ROWP2 (CURS + 12512)    // NN int2 (beg,end)
#define OFLB  (ROWP2 + 200000)  // [0] count; int2 entries from +2 (cap EE)
#define PEB   (OFLB + 3200004)  // NBUCK*CAP packed edges
#define SRCB  (PEB + 3203072)   // NBUCK*CAP + EE src lists (tail region for overflow)

// ---- param offsets inside PARB ----
#define O_WCONT 0
#define O_BCONT 96
#define O_TCHRG 112
#define O_TPDG  136
#define O_TPV   192
#define O_WCAT  256
#define O_BCAT  640
#define O_WENC  656
#define O_BENC  1680
#define O_GALL  1712
#define O_BEALL 1744
#define O_WMSG  1776
#define O_BMSG  3824
#define O_GCONV 3856
#define O_BECONV 3888
#define O_WOUT1 3920
#define O_BOUT1 4432
#define O_WOUT2 4448
#define O_BOUT2 4464
#define NPAR    4465

__device__ __forceinline__ float bf(unsigned short u) {
    return __uint_as_float(((unsigned)u) << 16);
}
__device__ __forceinline__ f4 elu4(f4 v) {
    f4 r;
    r.x = v.x > 0.0f ? v.x : expm1f(v.x);
    r.y = v.y > 0.0f ? v.y : expm1f(v.y);
    r.z = v.z > 0.0f ? v.z : expm1f(v.z);
    r.w = v.w > 0.0f ? v.w : expm1f(v.w);
    return r;
}
__device__ __forceinline__ f4 f4max(f4 a, f4 b) {
    f4 r;
    r.x = fmaxf(a.x, b.x); r.y = fmaxf(a.y, b.y);
    r.z = fmaxf(a.z, b.z); r.w = fmaxf(a.w, b.w);
    return r;
}

// ---------------- init: params + cursors + stats zero ----------------
struct InitArgs {
    const void* p[19];
    const unsigned short* wdet;   // d_in[11] (W_enc) raw, for dtype sniffing
    int*        flagw;
    float*      par;
    int*        curs;
    float*      stats;
    float*      part;
    int*        ofl;
    int*        tcur;
};

__global__ __launch_bounds__(256) void k_init(InitArgs a)
{
    const int offs[20] = {O_WCONT,O_BCONT,O_TCHRG,O_TPDG,O_TPV,O_WCAT,O_BCAT,O_WENC,
                          O_BENC,O_GALL,O_BEALL,O_WMSG,O_BMSG,O_GCONV,O_BECONV,
                          O_WOUT1,O_BOUT1,O_WOUT2,O_BOUT2,NPAR};
    __shared__ int sflag;
    int b = blockIdx.x, tid = threadIdx.x;
    int g = b * 256 + tid;
    if (g < NBUCK) a.curs[g * CPAD] = g << CAPSH;     // pre-baked bucket base cursor
    if (g < 4096) a.part[g] = 0.0f;
    if (g < 128) a.stats[g] = 0.0f;
    if (g == 0) { a.ofl[0] = 0; *a.tcur = NBUCK << CAPSH; }
    if (b == 0) {
        if (tid == 0) sflag = 0;
        __syncthreads();
        int bad = 0;
        for (int i = tid; i < 1024; i += 256) {
            unsigned e = (a.wdet[i] >> 7) & 0xFFu;
            if (e >= 137u) bad = 1;       // |v| >= 2^10 as bf16 -> impossible for weights
        }
        if (bad) atomicOr(&sflag, 1);
        __syncthreads();
        int f32 = sflag;
        if (tid == 0) *a.flagw = f32;
        for (int i = tid; i < NPAR; i += 256) {
            int t = 0;
            while (offs[t + 1] <= i) t++;
            int l = i - offs[t];
            const void* s = a.p[t];
            a.par[i] = f32 ? ((const float*)s)[l] : bf(((const unsigned short*)s)[l]);
        }
    }
}

// ---------------- fused A: partition (blocks 0..390) | embed+stats1 (391..781) ----------------
struct SMemPart { int cnt[NBUCK]; int start[NBUCK]; };
struct SMemEmb  { float wc[96], bc[16], tc[24], tp[56], tv[64],
                  wcat[384], bcat[16], we[1024], be[32], ls[64]; };
union SMemA { SMemPart p; SMemEmb e; };

__global__ __launch_bounds__(256, 1) void k_fA(
    const int* __restrict__ eidx, int* __restrict__ curs,
    int* __restrict__ pe, int* __restrict__ ofl, int2* __restrict__ ofl2,
    const void* __restrict__ xc, const int* __restrict__ x_cat,
    const float* __restrict__ par, const int* __restrict__ flag,
    float* __restrict__ emb, float* __restrict__ stats)
{
    __shared__ alignas(16) SMemA sm;
    int tid = threadIdx.x;
    int b = blockIdx.x;

    if (b < NPART) {
        // ---- partition: LDS count -> reserve -> place packed (src<<7)|(dst&127) ----
        for (int i = tid; i < NBUCK; i += 256) sm.p.cnt[i] = 0;
        __syncthreads();
        const int4v* src4 = (const int4v*)eidx;
        const int4v* dst4 = (const int4v*)(eidx + EE);
        int i0 = b << 10;
        int i1 = i0 + 1024; if (i1 > NE4) i1 = NE4;
        for (int i = i0 + tid; i < i1; i += 256) {
            int4v d = dst4[i];
            atomicAdd(&sm.p.cnt[d.x >> 7], 1);
            atomicAdd(&sm.p.cnt[d.y >> 7], 1);
            atomicAdd(&sm.p.cnt[d.z >> 7], 1);
            atomicAdd(&sm.p.cnt[d.w >> 7], 1);
        }
        __syncthreads();
        for (int i = tid; i < NBUCK; i += 256) {
            int c = sm.p.cnt[i];
            sm.p.start[i] = c ? atomicAdd(&curs[i * CPAD], c) : 0;
        }
        __syncthreads();
        for (int i = tid; i < NBUCK; i += 256) sm.p.cnt[i] = 0;
        __syncthreads();
        for (int i = i0 + tid; i < i1; i += 256) {
            int4v s = src4[i];
            int4v d = dst4[i];
            #define PLACE(SS, DD) { \
                int bk = (DD) >> 7; \
                int r = atomicAdd(&sm.p.cnt[bk], 1); \
                int slot = sm.p.start[bk] + r; \
                int packed = ((SS) << 7) | ((DD) & 127); \
                if (slot < ((bk + 1) << CAPSH)) pe[slot] = packed; \
                else { int oi = atomicAdd(ofl, 1); ofl2[oi] = make_int2(bk, packed); } }
            PLACE(s.x, d.x) PLACE(s.y, d.y) PLACE(s.z, d.z) PLACE(s.w, d.w)
            #undef PLACE
        }
        return;
    }

    // ---- embed path + fused bn1 stats ----
    {
        float* s;
        s=sm.e.wc;   for(int i=tid;i<96;  i+=256) s[i]=par[O_WCONT+i];
        s=sm.e.bc;   for(int i=tid;i<16;  i+=256) s[i]=par[O_BCONT+i];
        s=sm.e.tc;   for(int i=tid;i<24;  i+=256) s[i]=par[O_TCHRG+i];
        s=sm.e.tp;   for(int i=tid;i<56;  i+=256) s[i]=par[O_TPDG+i];
        s=sm.e.tv;   for(int i=tid;i<64;  i+=256) s[i]=par[O_TPV+i];
        s=sm.e.wcat; for(int i=tid;i<384; i+=256) s[i]=par[O_WCAT+i];
        s=sm.e.bcat; for(int i=tid;i<16;  i+=256) s[i]=par[O_BCAT+i];
        s=sm.e.we;   for(int i=tid;i<1024;i+=256) s[i]=par[O_WENC+i];
        s=sm.e.be;   for(int i=tid;i<32;  i+=256) s[i]=par[O_BENC+i];
        if (tid < 64) sm.e.ls[tid] = 0.0f;
    }
    __syncthreads();

    int n = (b - NPART) * 256 + tid;
    f4 esum[8], esq[8];
    #pragma unroll
    for (int g = 0; g < 8; g++) { esum[g] = (f4){0,0,0,0}; esq[g] = (f4){0,0,0,0}; }

    if (n < NN) {
        f4* sWc4 = (f4*)sm.e.wc;  f4* sbc4 = (f4*)sm.e.bc;
        f4* sTc4 = (f4*)sm.e.tc;  f4* sTp4 = (f4*)sm.e.tp;  f4* sTv4 = (f4*)sm.e.tv;
        f4* sWcat4 = (f4*)sm.e.wcat; f4* sbcat4 = (f4*)sm.e.bcat;
        f4* sWe4 = (f4*)sm.e.we;  f4* sbe4 = (f4*)sm.e.be;

        float x0,x1,x2,x3,x4,x5;
        if (*flag) {
            const float* xr = (const float*)xc + (size_t)n * 6;
            x0=xr[0]; x1=xr[1]; x2=xr[2]; x3=xr[3]; x4=xr[4]; x5=xr[5];
        } else {
            const unsigned* xr = (const unsigned*)xc + (size_t)n * 3;
            unsigned w0=xr[0], w1=xr[1], w2=xr[2];
            x0=__uint_as_float(w0<<16); x1=__uint_as_float(w0 & 0xFFFF0000u);
            x2=__uint_as_float(w1<<16); x3=__uint_as_float(w1 & 0xFFFF0000u);
            x4=__uint_as_float(w2<<16); x5=__uint_as_float(w2 & 0xFFFF0000u);
        }

        f4 ec[4];
        #pragma unroll
        for (int g = 0; g < 4; g++) {
            f4 acc = sbc4[g];
            acc += x0 * sWc4[0*4+g]; acc += x1 * sWc4[1*4+g]; acc += x2 * sWc4[2*4+g];
            acc += x3 * sWc4[3*4+g]; acc += x4 * sWc4[4*4+g]; acc += x5 * sWc4[5*4+g];
            ec[g] = elu4(acc);
        }

        int c0 = x_cat[n*3+0], c1 = x_cat[n*3+1], c2 = x_cat[n*3+2];
        int a0 = c0 < 0 ? -c0 : c0;
        int pi = (a0==1)?0:(a0==2)?1:(a0==11)?2:(a0==13)?3:(a0==22)?4:(a0==130)?5:6;
        int ci = c1 + 1;

        f4 t0a = sTc4[ci*2],  t0b = sTc4[ci*2+1];
        f4 t1a = sTp4[pi*2],  t1b = sTp4[pi*2+1];
        f4 t2a = sTv4[c2*2],  t2b = sTv4[c2*2+1];

        f4 ecat[4];
        #pragma unroll
        for (int g = 0; g < 4; g++) {
            f4 acc = sbcat4[g];
            #pragma unroll
            for (int k = 0; k < 4; k++) acc += t0a[k] * sWcat4[(k     )*4+g];
            #pragma unroll
            for (int k = 0; k < 4; k++) acc += t0b[k] * sWcat4[(4 + k )*4+g];
            #pragma unroll
            for (int k = 0; k < 4; k++) acc += t1a[k] * sWcat4[(8 + k )*4+g];
            #pragma unroll
            for (int k = 0; k < 4; k++) acc += t1b[k] * sWcat4[(12 + k)*4+g];
            #pragma unroll
            for (int k = 0; k < 4; k++) acc += t2a[k] * sWcat4[(16 + k)*4+g];
            #pragma unroll
            for (int k = 0; k < 4; k++) acc += t2b[k] * sWcat4[(20 + k)*4+g];
            ecat[g] = elu4(acc);
        }

        f4* o = (f4*)(emb + (size_t)n * 32);
        #pragma unroll
        for (int cg = 0; cg < 8; cg++) {
            f4 acc = sbe4[cg];
            #pragma unroll
            for (int kg = 0; kg < 4; kg++) {
                #pragma unroll
                for (int k = 0; k < 4; k++)
                    acc += ecat[kg][k] * sWe4[(kg*4+k)*8 + cg];
            }
            #pragma unroll
            for (int kg = 0; kg < 4; kg++) {
                #pragma unroll
                for (int k = 0; k < 4; k++)
                    acc += ec[kg][k] * sWe4[(16 + kg*4+k)*8 + cg];
            }
            f4 v = elu4(acc);
            o[cg] = v;
            esum[cg] = v;
            esq[cg]  = v * v;
        }
    }

    // wave butterfly reduce (channels are fixed vector positions)
    #pragma unroll
    for (int off = 1; off < 64; off <<= 1) {
        #pragma unroll
        for (int g = 0; g < 8; g++) {
            esum[g].x += __shfl_xor(esum[g].x, off);
            esum[g].y += __shfl_xor(esum[g].y, off);
            esum[g].z += __shfl_xor(esum[g].z, off);
            esum[g].w += __shfl_xor(esum[g].w, off);
            esq[g].x  += __shfl_xor(esq[g].x,  off);
            esq[g].y  += __shfl_xor(esq[g].y,  off);
            esq[g].z  += __shfl_xor(esq[g].z,  off);
            esq[g].w  += __shfl_xor(esq[g].w,  off);
        }
    }
    if ((tid & 63) == 0) {
        #pragma unroll
        for (int g = 0; g < 8; g++) {
            #pragma unroll
            for (int k = 0; k < 4; k++) {
                atomicAdd(&sm.e.ls[g*4+k],      esum[g][k]);
                atomicAdd(&sm.e.ls[32+g*4+k],   esq[g][k]);
            }
        }
    }
    __syncthreads();
    if (tid < 64) atomicAdd(&stats[tid], sm.e.ls[tid]);
}

// ---------------- fused B: per-bucket CSR (0..781) | P,Q build (782..1172) ----------------
struct SMemCsr { int stage[BCAP]; int cnt[128]; int sc[128]; int ex[128]; int tl; };
struct SMemPq  { float wp[1024], wq[1024], bp[32], bq[32], ssc[32], ssh[32]; };
union SMemB { SMemCsr c; SMemPq q; };

__global__ __launch_bounds__(256) void k_fB(
    const int* __restrict__ curs, const int* __restrict__ pe,
    const int* __restrict__ ofl, const int2* __restrict__ ofl2,
    int* __restrict__ tcur, int2* __restrict__ rowp2, int* __restrict__ srcl,
    const float* __restrict__ emb, const float* __restrict__ stats,
    const float* __restrict__ par, float* __restrict__ P, float* __restrict__ Q)
{
    __shared__ alignas(16) SMemB sm;
    int tid = threadIdx.x;
    int b = blockIdx.x;

    if (b < NBUCK) {
        int beg = b << CAPSH;
        int m_res = curs[b * CPAD] - beg;            // true bucket edge count
        int stored = m_res < CAP ? m_res : CAP;
        int no = ofl[0];                              // overflow entries (normally 0)
        if (tid < 128) sm.c.cnt[tid] = 0;
        __syncthreads();
        for (int i = tid; i < stored; i += 256) {
            int p = pe[beg + i];
            if (i < BCAP) sm.c.stage[i] = p;
            atomicAdd(&sm.c.cnt[p & 127], 1);
        }
        for (int j = tid; j < no; j += 256) {
            int2 oe = ofl2[j];
            if (oe.x == b) atomicAdd(&sm.c.cnt[oe.y & 127], 1);
        }
        __syncthreads();
        if (tid < 128) sm.c.sc[tid] = sm.c.cnt[tid];
        __syncthreads();
        for (int off = 1; off < 128; off <<= 1) {
            int x = (tid >= off && tid < 128) ? sm.c.sc[tid - off] : 0;
            __syncthreads();
            if (tid < 128) sm.c.sc[tid] += x;
            __syncthreads();
        }
        int obeg = beg;
        if (m_res > CAP) {                            // astronomically rare: tail-allocate
            if (tid == 0) sm.c.tl = atomicAdd(tcur, m_res);
            __syncthreads();
            obeg = sm.c.tl;
        }
        if (tid < 128) {
            int e0 = sm.c.sc[tid] - sm.c.cnt[tid];
            int deg = sm.c.cnt[tid];
            sm.c.ex[tid] = e0;
            int node = b * 128 + tid;
            if (node < NN) rowp2[node] = make_int2(obeg + e0, obeg + e0 + deg);
            sm.c.cnt[tid] = 0;
        }
        __syncthreads();
        for (int i = tid; i < stored; i += 256) {
            int p = (i < BCAP) ? sm.c.stage[i] : pe[beg + i];
            int dl = p & 127;
            int r = atomicAdd(&sm.c.cnt[dl], 1);
            srcl[obeg + sm.c.ex[dl] + r] = p >> 7;
        }
        for (int j = tid; j < no; j += 256) {
            int2 oe = ofl2[j];
            if (oe.x == b) {
                int dl = oe.y & 127;
                int r = atomicAdd(&sm.c.cnt[dl], 1);
                srcl[obeg + sm.c.ex[dl] + r] = oe.y >> 7;
            }
        }
        return;
    }

    // ---- P,Q build (bn1 + Wmsg folded) ----
    if (tid < 32) {
        float mu  = stats[tid] * (1.0f / NN);
        float var = stats[32 + tid] * (1.0f / NN) - mu * mu;
        float s   = par[O_GALL + tid] * rsqrtf(var + 1e-5f);
        sm.q.ssc[tid] = s;
        sm.q.ssh[tid] = par[O_BEALL + tid] - mu * s;
    }
    __syncthreads();
    for (int e = tid; e < 1024; e += 256) {
        int k = e >> 5;
        float w1 = par[O_WMSG + e];
        float w2 = par[O_WMSG + 1024 + e];
        sm.q.wp[e] = sm.q.ssc[k] * (w1 - w2);
        sm.q.wq[e] = sm.q.ssc[k] * w2;
    }
    if (tid < 32) {
        float aP = par[O_BMSG + tid], aQ = 0.0f;
        for (int k = 0; k < 32; k++) {
            float w1 = par[O_WMSG + k*32 + tid];
            float w2 = par[O_WMSG + (k+32)*32 + tid];
            aP += sm.q.ssh[k] * (w1 - w2);
            aQ += sm.q.ssh[k] * w2;
        }
        sm.q.bp[tid] = aP;
        sm.q.bq[tid] = aQ;
    }
    __syncthreads();

    int n = (b - NBUCK) * 256 + tid;
    if (n >= NN) return;

    f4* sWP4 = (f4*)sm.q.wp; f4* sWQ4 = (f4*)sm.q.wq;
    f4* sbP4 = (f4*)sm.q.bp; f4* sbQ4 = (f4*)sm.q.bq;
    const f4* er = (const f4*)(emb + (size_t)n * 32);
    f4 e[8];
    #pragma unroll
    for (int g = 0; g < 8; g++) e[g] = er[g];
    f4* pr = (f4*)(P + (size_t)n * 32);
    f4* qr = (f4*)(Q + (size_t)n * 32);
    #pragma unroll
    for (int cg = 0; cg < 8; cg++) {
        f4 aP = sbP4[cg];
        f4 aQ = sbQ4[cg];
        #pragma unroll
        for (int kg = 0; kg < 8; kg++) {
            #pragma unroll
            for (int k = 0; k < 4; k++) {
                float ek = e[kg][k];
                aP += ek * sWP4[(kg*4+k)*8 + cg];
                aQ += ek * sWQ4[(kg*4+k)*8 + cg];
            }
        }
        pr[cg] = aP;
        qr[cg] = aQ;
    }
}

// ---------------- gather-max + fused bn2 stats (64 replicated partials) ----------------
__global__ __launch_bounds__(256) void k_gather(
    const int2* __restrict__ rowp2, const int* __restrict__ srcl,
    const float* __restrict__ Q, const float* __restrict__ P,
    float* __restrict__ agg, float* __restrict__ part)
{
    __shared__ float ls[64];
    int tid = threadIdx.x;
    if (tid < 64) ls[tid] = 0.0f;
    __syncthreads();

    int lane = tid & 63;
    int wave = tid >> 6;
    int n = blockIdx.x * 4 + wave;       // 25000 blocks x 4 waves = 100000
    int slice = lane >> 3;               // 0..7 edge slice
    int cg    = lane & 7;                // channel group
    int2 be = rowp2[n];
    int beg = be.x, end = be.y;
    const f4* Q4 = (const f4*)Q;

    f4 pv = (f4){0.f, 0.f, 0.f, 0.f};
    if (lane < 8 && end > beg) pv = ((const f4*)P)[(size_t)n * 8 + lane];

    f4 m = {-INFINITY, -INFINITY, -INFINITY, -INFINITY};
    for (int e = beg + slice; e < end; e += 32) {
        int e1 = min(e + 8,  end - 1);
        int e2 = min(e + 16, end - 1);
        int e3 = min(e + 24, end - 1);
        int s0 = __builtin_nontemporal_load(&srcl[e]);
        int s1 = __builtin_nontemporal_load(&srcl[e1]);
        int s2 = __builtin_nontemporal_load(&srcl[e2]);
        int s3 = __builtin_nontemporal_load(&srcl[e3]);
        f4 q0 = Q4[(size_t)s0 * 8 + cg];
        f4 q1 = Q4[(size_t)s1 * 8 + cg];
        f4 q2 = Q4[(size_t)s2 * 8 + cg];
        f4 q3 = Q4[(size_t)s3 * 8 + cg];
        q0 = f4max(q0, q1);
        q2 = f4max(q2, q3);
        m = f4max(m, f4max(q0, q2));
    }
    #pragma unroll
    for (int off = 8; off < 64; off <<= 1) {
        m.x = fmaxf(m.x, __shfl_xor(m.x, off));
        m.y = fmaxf(m.y, __shfl_xor(m.y, off));
        m.z = fmaxf(m.z, __shfl_xor(m.z, off));
        m.w = fmaxf(m.w, __shfl_xor(m.w, off));
    }
    if (lane < 8) {
        f4 o;
        if (end > beg) o = m + pv;
        else           o = (f4){0.f, 0.f, 0.f, 0.f};
        ((f4*)agg)[(size_t)n * 8 + lane] = o;
        atomicAdd(&ls[cg*4+0], o.x);
        atomicAdd(&ls[cg*4+1], o.y);
        atomicAdd(&ls[cg*4+2], o.z);
        atomicAdd(&ls[cg*4+3], o.w);
        atomicAdd(&ls[32+cg*4+0], o.x*o.x);
        atomicAdd(&ls[32+cg*4+1], o.y*o.y);
        atomicAdd(&ls[32+cg*4+2], o.z*o.z);
        atomicAdd(&ls[32+cg*4+3], o.w*o.w);
    }
    __syncthreads();
    if (tid < 64) atomicAdd(&part[(blockIdx.x & 63) * 64 + tid], ls[tid]);
}

// ---------------- output MLP (+ bn2 partial reduction prologue) ----------------
__global__ __launch_bounds__(256, 1) void k_out(
    const float* __restrict__ emb, const float* __restrict__ agg,
    const float* __restrict__ par, const float* __restrict__ stats,
    const float* __restrict__ part,
    const int* __restrict__ flag, void* __restrict__ out)
{
    __shared__ f4 sW14[128];    // [32][16]
    __shared__ f4 sb14[4], sW24[4];
    __shared__ f4 sc14[8], sh14[8], sc24[8], sh24[8];
    __shared__ float spart[64];
    __shared__ float sb2s;
    int tid = threadIdx.x;
    {
        float* s = (float*)sW14;
        for (int i = tid; i < 512; i += 256) s[i] = par[O_WOUT1 + i];
    }
    if (tid < 16) {
        ((float*)sb14)[tid] = par[O_BOUT1 + tid];
        ((float*)sW24)[tid] = par[O_WOUT2 + tid];
    }
    if (tid < 64) {                         // reduce 64 bn2 replicas
        float acc2 = 0.0f;
        #pragma unroll 8
        for (int r = 0; r < 64; r++) acc2 += part[r * 64 + tid];
        spart[tid] = acc2;
    }
    if (tid == 0) sb2s = par[O_BOUT2];
    __syncthreads();
    if (tid < 32) {
        float mu  = stats[tid] * (1.0f / NN);
        float var = stats[32 + tid] * (1.0f / NN) - mu * mu;
        float s   = par[O_GALL + tid] * rsqrtf(var + 1e-5f);
        ((float*)sc14)[tid] = s;
        ((float*)sh14)[tid] = par[O_BEALL + tid] - mu * s;
        float mu2  = spart[tid] * (1.0f / NN);
        float var2 = spart[32 + tid] * (1.0f / NN) - mu2 * mu2;
        float s2   = par[O_GCONV + tid] * rsqrtf(var2 + 1e-5f);
        ((float*)sc24)[tid] = s2;
        ((float*)sh24)[tid] = par[O_BECONV + tid] - mu2 * s2;
    }
    __syncthreads();

    int n = blockIdx.x * 256 + tid;
    if (n >= NN) return;

    const f4* er = (const f4*)(emb + (size_t)n * 32);
    const f4* ar = (const f4*)(agg + (size_t)n * 32);
    f4 h[8];
    #pragma unroll
    for (int g = 0; g < 8; g++) {
        f4 ev = er[g];
        f4 av = ar[g];
        h[g] = ev * sc14[g] + sh14[g] + av * sc24[g] + sh24[g];
    }
    f4 o1[4];
    #pragma unroll
    for (int g = 0; g < 4; g++) {
        f4 acc = sb14[g];
        #pragma unroll
        for (int kg = 0; kg < 8; kg++) {
            #pragma unroll
            for (int k = 0; k < 4; k++)
                acc += h[kg][k] * sW14[(kg*4+k)*4 + g];
        }
        o1[g] = elu4(acc);
    }
    float acc = sb2s;
    #pragma unroll
    for (int g = 0; g < 4; g++) {
        f4 p = o1[g] * sW24[g];
        acc += p.x + p.y + p.z + p.w;
    }

    if (*flag) ((float*)out)[n] = acc;
    else       ((bf16_t*)out)[n] = __float2bfloat16(acc);
}

// ======================= launcher (5 dispatches) =======================

extern "C" void kernel_launch(void* const* d_in, const int* in_sizes, int n_in,
                              void* d_out, int out_size, void* d_ws, size_t ws_size,
                              hipStream_t stream)
{
    const void* x_cont = d_in[0];
    const int* x_cat = (const int*)d_in[1];
    const int* eidx  = (const int*)d_in[2];

    float* ws    = (float*)d_ws;
    float* par   = ws + PARB;
    float* emb   = ws + EMB;
    float* P     = ws + PBUF;
    float* Q     = ws + QBUF;
    float* agg   = ws + ABUF;
    float* stats = ws + SOFF;
    int*   flag  = (int*)(stats + 128);
    float* part  = ws + PART2;
    int*   curs  = (int*)(ws + CURS);
    int2*  rowp2 = (int2*)(ws + ROWP2);
    int*   ofl   = (int*)(ws + OFLB);
    int2*  ofl2  = (int2*)(ws + OFLB + 2);
    int*   pe    = (int*)(ws + PEB);
    int*   srcl  = (int*)(ws + SRCB);
    int*   tcur  = (int*)(stats + 130);

    InitArgs ia;
    for (int t = 0; t < 19; t++) ia.p[t] = d_in[4 + t];
    ia.wdet = (const unsigned short*)d_in[11];
    ia.flagw = flag; ia.par = par; ia.curs = curs; ia.stats = stats;
    ia.part = part; ia.ofl = ofl; ia.tcur = tcur;
    k_init<<<NB_SCAN, 256, 0, stream>>>(ia);

    k_fA<<<NPART + NB_SCAN, 256, 0, stream>>>(eidx, curs, pe, ofl, ofl2,
                                              x_cont, x_cat, par, flag, emb, stats);
    k_fB<<<NBUCK + NB_SCAN, 256, 0, stream>>>(curs, pe, ofl, ofl2, tcur, rowp2, srcl,
                                              emb, stats, par, P, Q);
    k_gather<<<NN / 4, 256, 0, stream>>>(rowp2, srcl, Q, P, agg, part);
    k_out<<<NB_SCAN, 256, 0, stream>>>(emb, agg, par, stats, part, flag, d_out);
}